// Round 1
// baseline (3768.866 us; speedup 1.0000x reference)
//
#include <hip/hip_runtime.h>
#include <math.h>

#define B_   2
#define T_   2048
#define DIM_ 2048
#define H_   16
#define DK_  128
#define DV_  128

__device__ __forceinline__ float sigmoidf_(float x) { return 1.0f / (1.0f + expf(-x)); }

// ---------------------------------------------------------------------------
// fp32 GEMM: C[M,N] = A[M,K] * B[K,N], row-major. 64x64 tile, BK=16, 4x4/thread.
// ---------------------------------------------------------------------------
__global__ __launch_bounds__(256) void gemm_f32(const float* __restrict__ A,
                                                const float* __restrict__ Bm,
                                                float* __restrict__ C,
                                                int M, int N, int K)
{
    __shared__ float As[16][68];  // [k][m], padded (68%4==0 keeps 16B align)
    __shared__ float Bs[16][68];  // [k][n]

    const int tid = threadIdx.x;
    const int bm = blockIdx.y * 64;
    const int bn = blockIdx.x * 64;

    const int tx = tid & 15;   // col group
    const int ty = tid >> 4;   // row group

    const int arow = tid >> 2;         // 0..63
    const int acol = (tid & 3) << 2;   // 0,4,8,12
    const int brow = tid >> 4;         // 0..15
    const int bcol = (tid & 15) << 2;  // 0..60

    float acc[4][4];
#pragma unroll
    for (int i = 0; i < 4; ++i)
#pragma unroll
        for (int j = 0; j < 4; ++j) acc[i][j] = 0.0f;

    for (int k0 = 0; k0 < K; k0 += 16) {
        float4 av = *(const float4*)(A + (size_t)(bm + arow) * K + k0 + acol);
        float4 bv = *(const float4*)(Bm + (size_t)(k0 + brow) * N + bn + bcol);

        __syncthreads();
        As[acol + 0][arow] = av.x;
        As[acol + 1][arow] = av.y;
        As[acol + 2][arow] = av.z;
        As[acol + 3][arow] = av.w;
        *(float4*)&Bs[brow][bcol] = bv;
        __syncthreads();

#pragma unroll
        for (int kk = 0; kk < 16; ++kk) {
            float a0 = As[kk][ty * 4 + 0];
            float a1 = As[kk][ty * 4 + 1];
            float a2 = As[kk][ty * 4 + 2];
            float a3 = As[kk][ty * 4 + 3];
            float b0 = Bs[kk][tx * 4 + 0];
            float b1 = Bs[kk][tx * 4 + 1];
            float b2 = Bs[kk][tx * 4 + 2];
            float b3 = Bs[kk][tx * 4 + 3];
            acc[0][0] += a0 * b0; acc[0][1] += a0 * b1; acc[0][2] += a0 * b2; acc[0][3] += a0 * b3;
            acc[1][0] += a1 * b0; acc[1][1] += a1 * b1; acc[1][2] += a1 * b2; acc[1][3] += a1 * b3;
            acc[2][0] += a2 * b0; acc[2][1] += a2 * b1; acc[2][2] += a2 * b2; acc[2][3] += a2 * b3;
            acc[3][0] += a3 * b0; acc[3][1] += a3 * b1; acc[3][2] += a3 * b2; acc[3][3] += a3 * b3;
        }
    }

#pragma unroll
    for (int i = 0; i < 4; ++i) {
        float4 v = make_float4(acc[i][0], acc[i][1], acc[i][2], acc[i][3]);
        *(float4*)(C + (size_t)(bm + ty * 4 + i) * N + bn + tx * 4) = v;
    }
}

// ---------------------------------------------------------------------------
// Depthwise causal conv (K=4) + bias, optional silu. x,y: [B][T][C], w: [C][4].
// ---------------------------------------------------------------------------
__global__ __launch_bounds__(256) void conv_kernel(const float* __restrict__ xin,
                                                   const float* __restrict__ w,
                                                   const float* __restrict__ bias,
                                                   float* __restrict__ y, int act)
{
    size_t idx = (size_t)blockIdx.x * 256 + threadIdx.x;  // < B*T*DIM
    int c = (int)(idx & (DIM_ - 1));
    int t = (int)((idx >> 11) & (T_ - 1));
    int b = (int)(idx >> 22);

    float acc = bias[c];
    const float* xc = xin + (size_t)b * T_ * DIM_ + c;
#pragma unroll
    for (int j = 0; j < 4; ++j) {
        int ts = t - 3 + j;
        if (ts >= 0) acc += xc[(size_t)ts * DIM_] * w[c * 4 + j];
    }
    if (act) acc = acc * sigmoidf_(acc);
    y[idx] = acc;
}

// ---------------------------------------------------------------------------
// L2-normalize k over each head's 128 dims. One wave per (b,t,h) row.
// ---------------------------------------------------------------------------
__global__ __launch_bounds__(256) void knorm_kernel(float* __restrict__ k)
{
    int lane = threadIdx.x & 63;
    int wv = threadIdx.x >> 6;
    size_t row = (size_t)blockIdx.x * 4 + wv;  // < B*T*H
    float2 val = *(float2*)(k + row * 128 + lane * 2);
    float ss = val.x * val.x + val.y * val.y;
#pragma unroll
    for (int off = 1; off < 64; off <<= 1) ss += __shfl_xor(ss, off);
    float scale = 1.0f / fmaxf(sqrtf(ss), 1e-12f);
    val.x *= scale;
    val.y *= scale;
    *(float2*)(k + row * 128 + lane * 2) = val;
}

// ---------------------------------------------------------------------------
// Direct recurrence. Grid: B*H*8 blocks; each block owns 16 v-rows of state.
// Thread t: v-row r = t>>4, d-slice sub = t&15 (8 state elems).
// ---------------------------------------------------------------------------
__global__ __launch_bounds__(256) void recur_kernel(const float* __restrict__ q,
                                                    const float* __restrict__ k,
                                                    const float* __restrict__ v,
                                                    const float* __restrict__ A_log,
                                                    const float* __restrict__ beta,
                                                    float* __restrict__ outs)
{
    int vg = blockIdx.x & 7;
    int h = (blockIdx.x >> 3) & (H_ - 1);
    int b = blockIdx.x >> 7;

    float decay = sigmoidf_(A_log[h]);
    float bet = sigmoidf_(beta[h]);

    int tid = threadIdx.x;
    int r = tid >> 4;        // 0..15 (local v-row)
    int sub = tid & 15;      // 0..15 (d slice)
    int d0 = sub << 3;

    __shared__ float kq[256];  // [0..127]=k, [128..255]=q
    __shared__ float vv[16];

    float st[8] = {0, 0, 0, 0, 0, 0, 0, 0};

    const float* kp = k + (size_t)b * T_ * DIM_ + h * DK_;
    const float* qp = q + (size_t)b * T_ * DIM_ + h * DK_;
    const float* vp = v + (size_t)b * T_ * DIM_ + h * DV_ + vg * 16;
    float* op = outs + (size_t)b * T_ * DIM_ + h * DV_ + vg * 16 + r;

    float lkq = (tid < 128) ? kp[tid] : qp[tid - 128];
    float lv = (tid < 16) ? vp[tid] : 0.0f;

    for (int t = 0; t < T_; ++t) {
        __syncthreads();  // prior step finished reading kq/vv
        kq[tid] = lkq;
        if (tid < 16) vv[tid] = lv;
        __syncthreads();

        if (t + 1 < T_) {  // prefetch next step (overlaps with compute below)
            size_t off = (size_t)(t + 1) * DIM_;
            lkq = (tid < 128) ? kp[off + tid] : qp[off + tid - 128];
            if (tid < 16) lv = vp[off + tid];
        }

        float tmp = bet * vv[r];
        float p = 0.0f;
#pragma unroll
        for (int i = 0; i < 8; ++i) {
            float kkv = kq[d0 + i];
            float qqv = kq[128 + d0 + i];
            st[i] = decay * st[i] + tmp * kkv;
            p += st[i] * qqv;
        }
        p += __shfl_xor(p, 1);
        p += __shfl_xor(p, 2);
        p += __shfl_xor(p, 4);
        p += __shfl_xor(p, 8);
        if (sub == 0) op[(size_t)t * DIM_] = p;
    }
}

// ---------------------------------------------------------------------------
// Output gating: o *= sigmoid(g), elementwise (float4 grid-stride).
// ---------------------------------------------------------------------------
__global__ __launch_bounds__(256) void gate_kernel(float* __restrict__ o,
                                                   const float* __restrict__ g, int n4)
{
    int i = blockIdx.x * 256 + threadIdx.x;
    int stride = gridDim.x * 256;
    for (; i < n4; i += stride) {
        float4 ov = ((const float4*)o)[i];
        float4 gv = ((const float4*)g)[i];
        ov.x *= sigmoidf_(gv.x);
        ov.y *= sigmoidf_(gv.y);
        ov.z *= sigmoidf_(gv.z);
        ov.w *= sigmoidf_(gv.w);
        ((float4*)o)[i] = ov;
    }
}

// ---------------------------------------------------------------------------
extern "C" void kernel_launch(void* const* d_in, const int* in_sizes, int n_in,
                              void* d_out, int out_size, void* d_ws, size_t ws_size,
                              hipStream_t stream)
{
    const float* x     = (const float*)d_in[0];
    const float* Wq    = (const float*)d_in[1];
    const float* Wk    = (const float*)d_in[2];
    const float* Wv    = (const float*)d_in[3];
    const float* Wo    = (const float*)d_in[4];
    const float* Wg    = (const float*)d_in[5];
    const float* qw    = (const float*)d_in[6];
    const float* qb    = (const float*)d_in[7];
    const float* kw    = (const float*)d_in[8];
    const float* kb    = (const float*)d_in[9];
    const float* vw    = (const float*)d_in[10];
    const float* vb    = (const float*)d_in[11];
    const float* beta  = (const float*)d_in[12];
    const float* A_log = (const float*)d_in[13];
    float* out = (float*)d_out;
    float* ws = (float*)d_ws;

    const size_t SZ = (size_t)B_ * T_ * DIM_;  // 8.4M floats = 32 MB
    float* p_q = ws + 0 * SZ;
    float* p_k = ws + 1 * SZ;
    float* p_v = ws + 2 * SZ;
    float* p_g = ws + 3 * SZ;
    float* c_q = ws + 4 * SZ;
    float* c_k = ws + 5 * SZ;
    float* c_v = ws + 6 * SZ;
    float* outs = p_q;  // p_q is dead after its conv

    const int M = B_ * T_;  // 4096
    dim3 gg(DIM_ / 64, M / 64);

    gemm_f32<<<gg, 256, 0, stream>>>(x, Wq, p_q, M, DIM_, DIM_);
    gemm_f32<<<gg, 256, 0, stream>>>(x, Wk, p_k, M, DIM_, DIM_);
    gemm_f32<<<gg, 256, 0, stream>>>(x, Wv, p_v, M, DIM_, DIM_);
    gemm_f32<<<gg, 256, 0, stream>>>(x, Wg, p_g, M, DIM_, DIM_);

    int nconv = (int)(SZ / 256);
    conv_kernel<<<nconv, 256, 0, stream>>>(p_q, qw, qb, c_q, 1);
    conv_kernel<<<nconv, 256, 0, stream>>>(p_k, kw, kb, c_k, 1);
    conv_kernel<<<nconv, 256, 0, stream>>>(p_v, vw, vb, c_v, 0);

    knorm_kernel<<<(B_ * T_ * H_) / 4, 256, 0, stream>>>(c_k);

    recur_kernel<<<B_ * H_ * 8, 256, 0, stream>>>(c_q, c_k, c_v, A_log, beta, outs);

    gate_kernel<<<8192, 256, 0, stream>>>(outs, p_g, (int)(SZ / 4));

    gemm_f32<<<gg, 256, 0, stream>>>(outs, Wo, out, M, DIM_, DIM_);
}

// Round 2
// 581.822 us; speedup vs baseline: 6.4777x; 6.4777x over previous
//
#include <hip/hip_runtime.h>
#include <math.h>

#define B_   2
#define T_   2048
#define DIM_ 2048
#define H_   16

typedef __attribute__((ext_vector_type(8))) _Float16 half8;
typedef __attribute__((ext_vector_type(4))) _Float16 half4;
typedef __attribute__((ext_vector_type(4))) float f32x4;

__device__ __forceinline__ float sigmoidf_(float x) { return 1.0f / (1.0f + __expf(-x)); }

__device__ __forceinline__ void gload16(const _Float16* g, _Float16* l) {
    __builtin_amdgcn_global_load_lds((const __attribute__((address_space(1))) void*)g,
                                     (__attribute__((address_space(3))) void*)l, 16, 0, 0);
}

// ---------------------------------------------------------------------------
// fp32 -> f16 elementwise convert (8/thread)
// ---------------------------------------------------------------------------
__global__ __launch_bounds__(256) void cvt_f16(const float* __restrict__ in,
                                               _Float16* __restrict__ out)
{
    size_t i = ((size_t)blockIdx.x * 256 + threadIdx.x) * 8;
    float4 a = *(const float4*)(in + i);
    float4 b = *(const float4*)(in + i + 4);
    half8 h;
    h[0] = (_Float16)a.x; h[1] = (_Float16)a.y; h[2] = (_Float16)a.z; h[3] = (_Float16)a.w;
    h[4] = (_Float16)b.x; h[5] = (_Float16)b.y; h[6] = (_Float16)b.z; h[7] = (_Float16)b.w;
    *(half8*)(out + i) = h;
}

// ---------------------------------------------------------------------------
// W[K][N] fp32 -> Wt[N][K] f16 (transpose + convert), 64x64 tiles
// ---------------------------------------------------------------------------
__global__ __launch_bounds__(256) void wconvT(const float* __restrict__ W,
                                              _Float16* __restrict__ Wt, int K, int N)
{
    __shared__ float t[64][65];
    const int c = threadIdx.x & 63;
    const int r0 = threadIdx.x >> 6;
    const int n0 = blockIdx.x * 64, k0 = blockIdx.y * 64;
#pragma unroll
    for (int i = 0; i < 16; ++i) {
        int r = i * 4 + r0;
        t[r][c] = W[(size_t)(k0 + r) * N + n0 + c];
    }
    __syncthreads();
#pragma unroll
    for (int i = 0; i < 16; ++i) {
        int r = i * 4 + r0;
        Wt[(size_t)(n0 + r) * K + k0 + c] = (_Float16)t[c][r];
    }
}

// ---------------------------------------------------------------------------
// f16 MFMA GEMM: C[M,N] = A[M,K] * Bt[N,K]^T.  128x128 tile, BK=32,
// 4 waves (2x2), 4x4 16x16x32 fragments per wave, global_load_lds staging.
// ---------------------------------------------------------------------------
template <typename OT>
__global__ __launch_bounds__(256) void gemm_f16(const _Float16* __restrict__ A,
                                                const _Float16* __restrict__ Bt,
                                                OT* __restrict__ C, int M, int N, int K)
{
    __shared__ _Float16 As[128 * 32];
    __shared__ _Float16 Bs[128 * 32];
    const int tid = threadIdx.x;
    const int lane = tid & 63, w = tid >> 6;
    const int wr = w >> 1, wc = w & 1;
    const int bm = blockIdx.y * 128, bn = blockIdx.x * 128;
    const int l15 = lane & 15, l16 = lane >> 4;

    const _Float16* Ag = A + (size_t)(bm + (tid >> 2)) * K + (tid & 3) * 8;
    const _Float16* Bg = Bt + (size_t)(bn + (tid >> 2)) * K + (tid & 3) * 8;
    _Float16* AsD0 = As + w * 512;
    _Float16* AsD1 = As + 2048 + w * 512;
    _Float16* BsD0 = Bs + w * 512;
    _Float16* BsD1 = Bs + 2048 + w * 512;
    const size_t rowoff = (size_t)64 * K;

    f32x4 acc[4][4] = {};

    for (int k0 = 0; k0 < K; k0 += 32) {
        __syncthreads();
        gload16(Ag + k0, AsD0);
        gload16(Ag + rowoff + k0, AsD1);
        gload16(Bg + k0, BsD0);
        gload16(Bg + rowoff + k0, BsD1);
        __syncthreads();
        half8 af[4], bf[4];
#pragma unroll
        for (int i = 0; i < 4; ++i)
            af[i] = *(const half8*)(As + (wr * 64 + i * 16 + l15) * 32 + l16 * 8);
#pragma unroll
        for (int j = 0; j < 4; ++j)
            bf[j] = *(const half8*)(Bs + (wc * 64 + j * 16 + l15) * 32 + l16 * 8);
#pragma unroll
        for (int i = 0; i < 4; ++i)
#pragma unroll
            for (int j = 0; j < 4; ++j)
                acc[i][j] = __builtin_amdgcn_mfma_f32_16x16x32_f16(af[i], bf[j], acc[i][j], 0, 0, 0);
    }

    const int crow = bm + wr * 64 + l16 * 4;
    const int ccol = bn + wc * 64 + l15;
#pragma unroll
    for (int i = 0; i < 4; ++i)
#pragma unroll
        for (int j = 0; j < 4; ++j)
#pragma unroll
            for (int r = 0; r < 4; ++r)
                C[(size_t)(crow + i * 16 + r) * N + ccol + j * 16] = (OT)acc[i][j][r];
}

// ---------------------------------------------------------------------------
// Depthwise causal conv K=4 + bias (+silu), f16 in/out, fp32 math.
// ---------------------------------------------------------------------------
__global__ __launch_bounds__(256) void conv_f16(const _Float16* __restrict__ xin,
                                                const float* __restrict__ w,
                                                const float* __restrict__ bias,
                                                _Float16* __restrict__ y, int act)
{
    size_t idx = (size_t)blockIdx.x * 256 + threadIdx.x;
    int cc = (int)(idx & (DIM_ - 1));
    int t = (int)((idx >> 11) & (T_ - 1));
    int b = (int)(idx >> 22);
    float acc = bias[cc];
    const _Float16* xc = xin + (size_t)b * T_ * DIM_ + cc;
#pragma unroll
    for (int j = 0; j < 4; ++j) {
        int ts = t - 3 + j;
        if (ts >= 0) acc += (float)xc[(size_t)ts * DIM_] * w[cc * 4 + j];
    }
    if (act) acc = acc * sigmoidf_(acc);
    y[idx] = (_Float16)acc;
}

// ---------------------------------------------------------------------------
// L2-normalize each 128-dim head row of k (f16 in/out, fp32 math)
// ---------------------------------------------------------------------------
__global__ __launch_bounds__(256) void knorm_f16(_Float16* __restrict__ k)
{
    int lane = threadIdx.x & 63, wv = threadIdx.x >> 6;
    size_t row = (size_t)blockIdx.x * 4 + wv;
    _Float16* p = k + row * 128 + lane * 2;
    float a = (float)p[0], b = (float)p[1];
    float ss = a * a + b * b;
#pragma unroll
    for (int off = 1; off < 64; off <<= 1) ss += __shfl_xor(ss, off);
    float sc = 1.0f / fmaxf(sqrtf(ss), 1e-12f);
    p[0] = (_Float16)(a * sc);
    p[1] = (_Float16)(b * sc);
}

// ---------------------------------------------------------------------------
// R1: per (bh, chunk) U_c = sum_s bet*decay^(63-s) * v_s k_s^T  (128x128 f16)
// ---------------------------------------------------------------------------
__global__ __launch_bounds__(256) void r1_kernel(const _Float16* __restrict__ kh,
                                                 const _Float16* __restrict__ vh,
                                                 const float* __restrict__ A_log,
                                                 const float* __restrict__ beta,
                                                 _Float16* __restrict__ U)
{
    const int c = blockIdx.x & 31, bh = blockIdx.x >> 5;
    const int h = bh & 15, b = bh >> 4;
    const float decay = sigmoidf_(A_log[h]);
    const float bet = sigmoidf_(beta[h]);
    const float ld = logf(decay);

    __shared__ _Float16 kt[128][72];  // k^T  (kt[j][s])
    __shared__ _Float16 vt[128][72];  // scaled v^T (vt[i][s])

    const int tid = threadIdx.x;
    const size_t base = ((size_t)(b * T_ + c * 64) * H_ + h) * 128;
    for (int rep = 0; rep < 32; ++rep) {
        int idx = rep * 256 + tid;
        int s = idx >> 7, i = idx & 127;
        float kv = (float)kh[base + (size_t)s * DIM_ + i];
        float vv = (float)vh[base + (size_t)s * DIM_ + i];
        kt[i][s] = (_Float16)kv;
        vt[i][s] = (_Float16)(bet * __expf(ld * (float)(63 - s)) * vv);
    }
    __syncthreads();

    const int lane = tid & 63, w = tid >> 6;
    const int l15 = lane & 15, l16 = lane >> 4;
    f32x4 acc[2][8] = {};
#pragma unroll
    for (int ks = 0; ks < 2; ++ks) {
        half8 a0 = *(const half8*)&vt[w * 32 + l15][ks * 32 + l16 * 8];
        half8 a1 = *(const half8*)&vt[w * 32 + 16 + l15][ks * 32 + l16 * 8];
#pragma unroll
        for (int fj = 0; fj < 8; ++fj) {
            half8 bf = *(const half8*)&kt[fj * 16 + l15][ks * 32 + l16 * 8];
            acc[0][fj] = __builtin_amdgcn_mfma_f32_16x16x32_f16(a0, bf, acc[0][fj], 0, 0, 0);
            acc[1][fj] = __builtin_amdgcn_mfma_f32_16x16x32_f16(a1, bf, acc[1][fj], 0, 0, 0);
        }
    }
    _Float16* Ub = U + (((size_t)blockIdx.x) << 14);
#pragma unroll
    for (int fi = 0; fi < 2; ++fi)
#pragma unroll
        for (int fj = 0; fj < 8; ++fj)
#pragma unroll
            for (int r = 0; r < 4; ++r) {
                int i = w * 32 + fi * 16 + l16 * 4 + r;
                int j = fj * 16 + l15;
                Ub[i * 128 + j] = (_Float16)acc[fi][fj][r];
            }
}

// ---------------------------------------------------------------------------
// R2: sequential chunk scan per (bh): S_pref[c] = state BEFORE chunk c.
// ---------------------------------------------------------------------------
__global__ __launch_bounds__(256) void r2_kernel(const _Float16* __restrict__ U,
                                                 _Float16* __restrict__ S,
                                                 const float* __restrict__ A_log)
{
    const int bh = blockIdx.x, h = bh & 15;
    const float decay = sigmoidf_(A_log[h]);
    const float d64 = __expf(64.0f * logf(decay));
    const int tid = threadIdx.x;
    float st[64];
#pragma unroll
    for (int j = 0; j < 64; ++j) st[j] = 0.0f;
    for (int c = 0; c < 32; ++c) {
        const size_t base = ((size_t)(bh * 32 + c)) << 14;
#pragma unroll
        for (int j = 0; j < 64; ++j) {
            int idx = j * 256 + tid;
            S[base + idx] = (_Float16)st[j];
            st[j] = d64 * st[j] + (float)U[base + idx];
        }
    }
}

// ---------------------------------------------------------------------------
// R3: per (bh, chunk): out = mask(QK^T)V + rowscale(Q S^T)
// ---------------------------------------------------------------------------
__global__ __launch_bounds__(256) void r3_kernel(const _Float16* __restrict__ qh,
                                                 const _Float16* __restrict__ kh,
                                                 const _Float16* __restrict__ vh,
                                                 const _Float16* __restrict__ S,
                                                 const float* __restrict__ A_log,
                                                 const float* __restrict__ beta,
                                                 float* __restrict__ outs)
{
    const int c = blockIdx.x & 31, bh = blockIdx.x >> 5;
    const int h = bh & 15, b = bh >> 4;
    const float decay = sigmoidf_(A_log[h]);
    const float bet = sigmoidf_(beta[h]);
    const float ld = logf(decay);

    __shared__ _Float16 vt[128][72];  // v^T
    __shared__ _Float16 ps[64][72];   // masked P

    const int tid = threadIdx.x;
    const size_t base = ((size_t)(b * T_ + c * 64) * H_ + h) * 128;
    for (int rep = 0; rep < 32; ++rep) {
        int idx = rep * 256 + tid;
        int s = idx >> 7, n = idx & 127;
        vt[n][s] = vh[base + (size_t)s * DIM_ + n];
    }
    __syncthreads();

    const int lane = tid & 63, w = tid >> 6;
    const int l15 = lane & 15, l16 = lane >> 4;

    // Q fragments (registers), rows w*16 .. w*16+15
    const _Float16* qrow = qh + base + (size_t)(w * 16 + l15) * DIM_;
    half8 af[4];
#pragma unroll
    for (int kd = 0; kd < 4; ++kd) af[kd] = *(const half8*)(qrow + kd * 32 + l16 * 8);

    // P = Q K^T (B-frags direct from global)
    f32x4 pacc[4] = {};
    const _Float16* kb = kh + base;
#pragma unroll
    for (int sf = 0; sf < 4; ++sf)
#pragma unroll
        for (int kd = 0; kd < 4; ++kd) {
            half8 bf = *(const half8*)(kb + (size_t)(sf * 16 + l15) * DIM_ + kd * 32 + l16 * 8);
            pacc[sf] = __builtin_amdgcn_mfma_f32_16x16x32_f16(af[kd], bf, pacc[sf], 0, 0, 0);
        }
    // mask + scale, store to LDS for A-operand relayout
#pragma unroll
    for (int sf = 0; sf < 4; ++sf)
#pragma unroll
        for (int r = 0; r < 4; ++r) {
            int tl = w * 16 + l16 * 4 + r;
            int s = sf * 16 + l15;
            float f = (s <= tl) ? bet * __expf(ld * (float)(tl - s)) : 0.0f;
            ps[tl][s] = (_Float16)(pacc[sf][r] * f);
        }
    __syncthreads();

    half8 pf[2];
#pragma unroll
    for (int ks = 0; ks < 2; ++ks)
        pf[ks] = *(const half8*)&ps[w * 16 + l15][ks * 32 + l16 * 8];

    f32x4 acc1[8] = {};  // inter (Q S^T)
    f32x4 acc2[8] = {};  // intra (P V)
    const _Float16* Sb = S + (((size_t)blockIdx.x) << 14);
#pragma unroll
    for (int nf = 0; nf < 8; ++nf) {
#pragma unroll
        for (int kd = 0; kd < 4; ++kd) {
            half8 bf = *(const half8*)(Sb + (size_t)(nf * 16 + l15) * 128 + kd * 32 + l16 * 8);
            acc1[nf] = __builtin_amdgcn_mfma_f32_16x16x32_f16(af[kd], bf, acc1[nf], 0, 0, 0);
        }
#pragma unroll
        for (int ks = 0; ks < 2; ++ks) {
            half8 bf = *(const half8*)&vt[nf * 16 + l15][ks * 32 + l16 * 8];
            acc2[nf] = __builtin_amdgcn_mfma_f32_16x16x32_f16(pf[ks], bf, acc2[nf], 0, 0, 0);
        }
    }
#pragma unroll
    for (int nf = 0; nf < 8; ++nf)
#pragma unroll
        for (int r = 0; r < 4; ++r) {
            int tl = w * 16 + l16 * 4 + r;
            int n = nf * 16 + l15;
            float o = acc2[nf][r] + __expf(ld * (float)(tl + 1)) * acc1[nf][r];
            outs[(size_t)(b * T_ + c * 64 + tl) * DIM_ + h * 128 + n] = o;
        }
}

// ---------------------------------------------------------------------------
// gate: gated = f16( outs * sigmoid(pg) )
// ---------------------------------------------------------------------------
__global__ __launch_bounds__(256) void gate_f16(const float* __restrict__ o,
                                                const _Float16* __restrict__ g,
                                                _Float16* __restrict__ out)
{
    size_t i = ((size_t)blockIdx.x * 256 + threadIdx.x) * 4;
    float4 ov = *(const float4*)(o + i);
    half4 gv = *(const half4*)(g + i);
    half4 r;
    r[0] = (_Float16)(ov.x * sigmoidf_((float)gv[0]));
    r[1] = (_Float16)(ov.y * sigmoidf_((float)gv[1]));
    r[2] = (_Float16)(ov.z * sigmoidf_((float)gv[2]));
    r[3] = (_Float16)(ov.w * sigmoidf_((float)gv[3]));
    *(half4*)(out + i) = r;
}

// ---------------------------------------------------------------------------
extern "C" void kernel_launch(void* const* d_in, const int* in_sizes, int n_in,
                              void* d_out, int out_size, void* d_ws, size_t ws_size,
                              hipStream_t stream)
{
    const float* x     = (const float*)d_in[0];
    const float* Wq    = (const float*)d_in[1];
    const float* Wk    = (const float*)d_in[2];
    const float* Wv    = (const float*)d_in[3];
    const float* Wo    = (const float*)d_in[4];
    const float* Wg    = (const float*)d_in[5];
    const float* qw    = (const float*)d_in[6];
    const float* qb    = (const float*)d_in[7];
    const float* kw    = (const float*)d_in[8];
    const float* kb    = (const float*)d_in[9];
    const float* vw    = (const float*)d_in[10];
    const float* vb    = (const float*)d_in[11];
    const float* beta  = (const float*)d_in[12];
    const float* A_log = (const float*)d_in[13];
    float* out = (float*)d_out;

    char* wsb = (char*)d_ws;
    const size_t WT  = (size_t)DIM_ * DIM_ * 2;   // f16 weight bytes
    const size_t SZ  = (size_t)B_ * T_ * DIM_;    // elements
    const size_t SZH = SZ * 2;                    // f16 buffer bytes

    _Float16* wtq = (_Float16*)(wsb + 0 * WT);
    _Float16* wtk = (_Float16*)(wsb + 1 * WT);
    _Float16* wtv = (_Float16*)(wsb + 2 * WT);
    _Float16* wtg = (_Float16*)(wsb + 3 * WT);
    _Float16* wto = (_Float16*)(wsb + 4 * WT);
    char* pbase = wsb + 5 * WT;
    _Float16* pq = (_Float16*)(pbase + 0 * SZH);
    _Float16* pk = (_Float16*)(pbase + 1 * SZH);
    _Float16* xh = (_Float16*)(pbase + 2 * SZH);
    _Float16* pv = (_Float16*)(pbase + 3 * SZH);
    _Float16* pg = (_Float16*)(pbase + 4 * SZH);
    _Float16* qh = (_Float16*)(pbase + 5 * SZH);
    _Float16* kh = (_Float16*)(pbase + 6 * SZH);
    _Float16* vh = (_Float16*)(pbase + 7 * SZH);
    float*    outs = (float*)(pbase + 8 * SZH);
    _Float16* U    = pq;   // 2*SZH, spans pq..pk (dead after convs)
    _Float16* Sst  = xh;   // 2*SZH, spans xh..pv (dead after GEMMs/convs)
    _Float16* gated = pq;  // 1*SZH, after R2 (U dead)

    const int M = B_ * T_;  // 4096

    cvt_f16<<<(int)(SZ / 2048), 256, 0, stream>>>(x, xh);
    dim3 tg(DIM_ / 64, DIM_ / 64);
    wconvT<<<tg, 256, 0, stream>>>(Wq, wtq, DIM_, DIM_);
    wconvT<<<tg, 256, 0, stream>>>(Wk, wtk, DIM_, DIM_);
    wconvT<<<tg, 256, 0, stream>>>(Wv, wtv, DIM_, DIM_);
    wconvT<<<tg, 256, 0, stream>>>(Wg, wtg, DIM_, DIM_);
    wconvT<<<tg, 256, 0, stream>>>(Wo, wto, DIM_, DIM_);

    dim3 gg(DIM_ / 128, M / 128);
    gemm_f16<_Float16><<<gg, 256, 0, stream>>>(xh, wtq, pq, M, DIM_, DIM_);
    gemm_f16<_Float16><<<gg, 256, 0, stream>>>(xh, wtk, pk, M, DIM_, DIM_);
    gemm_f16<_Float16><<<gg, 256, 0, stream>>>(xh, wtv, pv, M, DIM_, DIM_);
    gemm_f16<_Float16><<<gg, 256, 0, stream>>>(xh, wtg, pg, M, DIM_, DIM_);

    conv_f16<<<(int)(SZ / 256), 256, 0, stream>>>(pq, qw, qb, qh, 1);
    conv_f16<<<(int)(SZ / 256), 256, 0, stream>>>(pk, kw, kb, kh, 1);
    conv_f16<<<(int)(SZ / 256), 256, 0, stream>>>(pv, vw, vb, vh, 0);

    knorm_f16<<<(B_ * T_ * H_) / 4, 256, 0, stream>>>(kh);

    r1_kernel<<<B_ * H_ * 32, 256, 0, stream>>>(kh, vh, A_log, beta, U);
    r2_kernel<<<B_ * H_, 256, 0, stream>>>(U, Sst, A_log);
    r3_kernel<<<B_ * H_ * 32, 256, 0, stream>>>(qh, kh, vh, Sst, A_log, beta, outs);

    gate_f16<<<(int)(SZ / 1024), 256, 0, stream>>>(outs, pg, gated);

    gemm_f16<float><<<gg, 256, 0, stream>>>(gated, wto, out, M, DIM_, DIM_);
}

// Round 3
// 508.780 us; speedup vs baseline: 7.4077x; 1.1436x over previous
//
#include <hip/hip_runtime.h>
#include <math.h>

#define B_   2
#define T_   2048
#define DIM_ 2048
#define H_   16

typedef __attribute__((ext_vector_type(8))) _Float16 half8;
typedef __attribute__((ext_vector_type(4))) _Float16 half4;
typedef __attribute__((ext_vector_type(4))) float f32x4;

__device__ __forceinline__ float sigmoidf_(float x) { return 1.0f / (1.0f + __expf(-x)); }

__device__ __forceinline__ void gload16(const _Float16* g, _Float16* l) {
    __builtin_amdgcn_global_load_lds((const __attribute__((address_space(1))) void*)g,
                                     (__attribute__((address_space(3))) void*)l, 16, 0, 0);
}

// ---------------------------------------------------------------------------
// fp32 -> f16 elementwise convert (8/thread)
// ---------------------------------------------------------------------------
__global__ __launch_bounds__(256) void cvt_f16(const float* __restrict__ in,
                                               _Float16* __restrict__ out)
{
    size_t i = ((size_t)blockIdx.x * 256 + threadIdx.x) * 8;
    float4 a = *(const float4*)(in + i);
    float4 b = *(const float4*)(in + i + 4);
    half8 h;
    h[0] = (_Float16)a.x; h[1] = (_Float16)a.y; h[2] = (_Float16)a.z; h[3] = (_Float16)a.w;
    h[4] = (_Float16)b.x; h[5] = (_Float16)b.y; h[6] = (_Float16)b.z; h[7] = (_Float16)b.w;
    *(half8*)(out + i) = h;
}

// ---------------------------------------------------------------------------
// W[K][N] fp32 -> Wt[N][K] f16 (transpose + convert), 64x64 tiles
// ---------------------------------------------------------------------------
__global__ __launch_bounds__(256) void wconvT(const float* __restrict__ W,
                                              _Float16* __restrict__ Wt, int K, int N)
{
    __shared__ float t[64][65];
    const int c = threadIdx.x & 63;
    const int r0 = threadIdx.x >> 6;
    const int n0 = blockIdx.x * 64, k0 = blockIdx.y * 64;
#pragma unroll
    for (int i = 0; i < 16; ++i) {
        int r = i * 4 + r0;
        t[r][c] = W[(size_t)(k0 + r) * N + n0 + c];
    }
    __syncthreads();
#pragma unroll
    for (int i = 0; i < 16; ++i) {
        int r = i * 4 + r0;
        Wt[(size_t)(n0 + r) * K + k0 + c] = (_Float16)t[c][r];
    }
}

// ---------------------------------------------------------------------------
// f16 MFMA GEMM: C = A[M,K] * Bt[N,K]^T. 128x128 tile, BK=32, m97 structure.
// 1D grid with XCD swizzle; epilogue splits N into up to 4 output buffers
// (each 2048 cols wide, row stride 2048).
// ---------------------------------------------------------------------------
template <typename OT>
__global__ __launch_bounds__(256) void gemm_f16(const _Float16* __restrict__ A,
                                                const _Float16* __restrict__ Bt,
                                                OT* __restrict__ C0, OT* __restrict__ C1,
                                                OT* __restrict__ C2, OT* __restrict__ C3,
                                                int K, int nx, int cpx)
{
    __shared__ _Float16 As[128 * 32];
    __shared__ _Float16 Bs[128 * 32];
    const int tid = threadIdx.x;
    const int lane = tid & 63, w = tid >> 6;
    const int wr = w >> 1, wc = w & 1;

    const int bid = blockIdx.x;
    const int swz = (bid & 7) * cpx + (bid >> 3);   // XCD-aware remap (nwg%8==0)
    const int bx = swz % nx, by = swz / nx;
    const int bm = by * 128, bn = bx * 128;

    const int l15 = lane & 15, l16 = lane >> 4;

    const _Float16* Ag = A + (size_t)(bm + (tid >> 2)) * K + (tid & 3) * 8;
    const _Float16* Bg = Bt + (size_t)(bn + (tid >> 2)) * K + (tid & 3) * 8;
    _Float16* AsD0 = As + w * 512;
    _Float16* AsD1 = As + 2048 + w * 512;
    _Float16* BsD0 = Bs + w * 512;
    _Float16* BsD1 = Bs + 2048 + w * 512;
    const size_t rowoff = (size_t)64 * K;

    f32x4 acc[4][4] = {};

    for (int k0 = 0; k0 < K; k0 += 32) {
        __syncthreads();
        gload16(Ag + k0, AsD0);
        gload16(Ag + rowoff + k0, AsD1);
        gload16(Bg + k0, BsD0);
        gload16(Bg + rowoff + k0, BsD1);
        __syncthreads();
        half8 af[4], bf[4];
#pragma unroll
        for (int i = 0; i < 4; ++i)
            af[i] = *(const half8*)(As + (wr * 64 + i * 16 + l15) * 32 + l16 * 8);
#pragma unroll
        for (int j = 0; j < 4; ++j)
            bf[j] = *(const half8*)(Bs + (wc * 64 + j * 16 + l15) * 32 + l16 * 8);
#pragma unroll
        for (int i = 0; i < 4; ++i)
#pragma unroll
            for (int j = 0; j < 4; ++j)
                acc[i][j] = __builtin_amdgcn_mfma_f32_16x16x32_f16(af[i], bf[j], acc[i][j], 0, 0, 0);
    }

    const int sel = bn >> 11;
    OT* __restrict__ C = sel == 0 ? C0 : sel == 1 ? C1 : sel == 2 ? C2 : C3;
    const int crow = bm + wr * 64 + l16 * 4;
    const int ccol = (bn & 2047) + wc * 64 + l15;
#pragma unroll
    for (int i = 0; i < 4; ++i)
#pragma unroll
        for (int j = 0; j < 4; ++j)
#pragma unroll
            for (int r = 0; r < 4; ++r)
                C[(size_t)(crow + i * 16 + r) * 2048 + ccol + j * 16] = (OT)acc[i][j][r];
}

// ---------------------------------------------------------------------------
// Depthwise causal conv K=4 + bias (+silu), f16 in/out, fp32 math.
// ---------------------------------------------------------------------------
__global__ __launch_bounds__(256) void conv_f16(const _Float16* __restrict__ xin,
                                                const float* __restrict__ w,
                                                const float* __restrict__ bias,
                                                _Float16* __restrict__ y, int act)
{
    size_t idx = (size_t)blockIdx.x * 256 + threadIdx.x;
    int cc = (int)(idx & (DIM_ - 1));
    int t = (int)((idx >> 11) & (T_ - 1));
    int b = (int)(idx >> 22);
    float acc = bias[cc];
    const _Float16* xc = xin + (size_t)b * T_ * DIM_ + cc;
#pragma unroll
    for (int j = 0; j < 4; ++j) {
        int ts = t - 3 + j;
        if (ts >= 0) acc += (float)xc[(size_t)ts * DIM_] * w[cc * 4 + j];
    }
    if (act) acc = acc * sigmoidf_(acc);
    y[idx] = (_Float16)acc;
}

// ---------------------------------------------------------------------------
// conv_k + silu + L2-normalize fused: one wave per (b,t,h) row, 2 ch/lane.
// ---------------------------------------------------------------------------
__global__ __launch_bounds__(256) void conv_knorm(const _Float16* __restrict__ xin,
                                                  const float* __restrict__ w,
                                                  const float* __restrict__ bias,
                                                  _Float16* __restrict__ kh)
{
    int lane = threadIdx.x & 63, wv = threadIdx.x >> 6;
    size_t r = (size_t)blockIdx.x * 4 + wv;   // (b*T+t)*H + h
    int h = (int)(r & 15);
    size_t gr = r >> 4;                       // b*T + t
    int t = (int)(gr & (T_ - 1));
    int c0 = h * 128 + lane * 2;

    float a0 = bias[c0], a1 = bias[c0 + 1];
#pragma unroll
    for (int j = 0; j < 4; ++j) {
        int ts = t - 3 + j;
        if (ts >= 0) {
            const _Float16* p = xin + (gr - 3 + j) * DIM_ + c0;
            a0 += (float)p[0] * w[c0 * 4 + j];
            a1 += (float)p[1] * w[(c0 + 1) * 4 + j];
        }
    }
    a0 = a0 * sigmoidf_(a0);
    a1 = a1 * sigmoidf_(a1);
    float ss = a0 * a0 + a1 * a1;
#pragma unroll
    for (int off = 1; off < 64; off <<= 1) ss += __shfl_xor(ss, off);
    float sc = 1.0f / fmaxf(sqrtf(ss), 1e-12f);
    kh[gr * DIM_ + c0]     = (_Float16)(a0 * sc);
    kh[gr * DIM_ + c0 + 1] = (_Float16)(a1 * sc);
}

// ---------------------------------------------------------------------------
// R1: per (bh, chunk) U_c = sum_s bet*decay^(63-s) * v_s k_s^T  (128x128 f16)
// ---------------------------------------------------------------------------
__global__ __launch_bounds__(256) void r1_kernel(const _Float16* __restrict__ kh,
                                                 const _Float16* __restrict__ vh,
                                                 const float* __restrict__ A_log,
                                                 const float* __restrict__ beta,
                                                 _Float16* __restrict__ U)
{
    const int c = blockIdx.x & 31, bh = blockIdx.x >> 5;
    const int h = bh & 15, b = bh >> 4;
    const float decay = sigmoidf_(A_log[h]);
    const float bet = sigmoidf_(beta[h]);
    const float ld = logf(decay);

    __shared__ _Float16 kt[128][72];  // k^T  (kt[j][s])
    __shared__ _Float16 vt[128][72];  // scaled v^T (vt[i][s])

    const int tid = threadIdx.x;
    const size_t base = ((size_t)(b * T_ + c * 64) * H_ + h) * 128;
    for (int rep = 0; rep < 32; ++rep) {
        int idx = rep * 256 + tid;
        int s = idx >> 7, i = idx & 127;
        float kv = (float)kh[base + (size_t)s * DIM_ + i];
        float vv = (float)vh[base + (size_t)s * DIM_ + i];
        kt[i][s] = (_Float16)kv;
        vt[i][s] = (_Float16)(bet * __expf(ld * (float)(63 - s)) * vv);
    }
    __syncthreads();

    const int lane = tid & 63, w = tid >> 6;
    const int l15 = lane & 15, l16 = lane >> 4;
    f32x4 acc[2][8] = {};
#pragma unroll
    for (int ks = 0; ks < 2; ++ks) {
        half8 a0 = *(const half8*)&vt[w * 32 + l15][ks * 32 + l16 * 8];
        half8 a1 = *(const half8*)&vt[w * 32 + 16 + l15][ks * 32 + l16 * 8];
#pragma unroll
        for (int fj = 0; fj < 8; ++fj) {
            half8 bf = *(const half8*)&kt[fj * 16 + l15][ks * 32 + l16 * 8];
            acc[0][fj] = __builtin_amdgcn_mfma_f32_16x16x32_f16(a0, bf, acc[0][fj], 0, 0, 0);
            acc[1][fj] = __builtin_amdgcn_mfma_f32_16x16x32_f16(a1, bf, acc[1][fj], 0, 0, 0);
        }
    }
    _Float16* Ub = U + (((size_t)blockIdx.x) << 14);
#pragma unroll
    for (int fi = 0; fi < 2; ++fi)
#pragma unroll
        for (int fj = 0; fj < 8; ++fj)
#pragma unroll
            for (int r = 0; r < 4; ++r) {
                int i = w * 32 + fi * 16 + l16 * 4 + r;
                int j = fj * 16 + l15;
                Ub[i * 128 + j] = (_Float16)acc[fi][fj][r];
            }
}

// ---------------------------------------------------------------------------
// R2: chunk-boundary state scan, parallel over (bh, 2048-elem slices).
// Grid: 256 blocks (8 per bh); thread owns 8 consecutive f16 state elems.
// ---------------------------------------------------------------------------
__global__ __launch_bounds__(256) void r2_kernel(const _Float16* __restrict__ U,
                                                 _Float16* __restrict__ S,
                                                 const float* __restrict__ A_log)
{
    const int blk = blockIdx.x;
    const int bh = blk >> 3, part = blk & 7, h = bh & 15;
    const float decay = sigmoidf_(A_log[h]);
    const float d64 = __expf(64.0f * logf(decay));
    const size_t base = ((size_t)bh << 19) + (size_t)part * 2048 + (size_t)threadIdx.x * 8;
    const half8* Up = (const half8*)(U + base);
    half8* Sp = (half8*)(S + base);

    float st[8] = {0, 0, 0, 0, 0, 0, 0, 0};
    half8 n0 = Up[0];
    half8 n1 = Up[2048];
    for (int c = 0; c < 32; ++c) {
        half8 cur = n0;
        n0 = n1;
        if (c + 2 < 32) n1 = Up[(size_t)(c + 2) * 2048];
        half8 so;
#pragma unroll
        for (int i = 0; i < 8; ++i) {
            so[i] = (_Float16)st[i];
            st[i] = d64 * st[i] + (float)cur[i];
        }
        Sp[(size_t)c * 2048] = so;
    }
}

// ---------------------------------------------------------------------------
// R3: per (bh, chunk): out = mask(QK^T)V + rowscale(Q S^T); gate fused.
// ---------------------------------------------------------------------------
__global__ __launch_bounds__(256) void r3_kernel(const _Float16* __restrict__ qh,
                                                 const _Float16* __restrict__ kh,
                                                 const _Float16* __restrict__ vh,
                                                 const _Float16* __restrict__ S,
                                                 const _Float16* __restrict__ pg,
                                                 const float* __restrict__ A_log,
                                                 const float* __restrict__ beta,
                                                 _Float16* __restrict__ gated)
{
    const int c = blockIdx.x & 31, bh = blockIdx.x >> 5;
    const int h = bh & 15, b = bh >> 4;
    const float decay = sigmoidf_(A_log[h]);
    const float bet = sigmoidf_(beta[h]);
    const float ld = logf(decay);

    __shared__ _Float16 vt[128][72];  // v^T
    __shared__ _Float16 ps[64][72];   // masked P

    const int tid = threadIdx.x;
    const size_t base = ((size_t)(b * T_ + c * 64) * H_ + h) * 128;
    for (int rep = 0; rep < 32; ++rep) {
        int idx = rep * 256 + tid;
        int s = idx >> 7, n = idx & 127;
        vt[n][s] = vh[base + (size_t)s * DIM_ + n];
    }
    __syncthreads();

    const int lane = tid & 63, w = tid >> 6;
    const int l15 = lane & 15, l16 = lane >> 4;

    const _Float16* qrow = qh + base + (size_t)(w * 16 + l15) * DIM_;
    half8 af[4];
#pragma unroll
    for (int kd = 0; kd < 4; ++kd) af[kd] = *(const half8*)(qrow + kd * 32 + l16 * 8);

    f32x4 pacc[4] = {};
    const _Float16* kb = kh + base;
#pragma unroll
    for (int sf = 0; sf < 4; ++sf)
#pragma unroll
        for (int kd = 0; kd < 4; ++kd) {
            half8 bf = *(const half8*)(kb + (size_t)(sf * 16 + l15) * DIM_ + kd * 32 + l16 * 8);
            pacc[sf] = __builtin_amdgcn_mfma_f32_16x16x32_f16(af[kd], bf, pacc[sf], 0, 0, 0);
        }
#pragma unroll
    for (int sf = 0; sf < 4; ++sf)
#pragma unroll
        for (int r = 0; r < 4; ++r) {
            int tl = w * 16 + l16 * 4 + r;
            int s = sf * 16 + l15;
            float f = (s <= tl) ? bet * __expf(ld * (float)(tl - s)) : 0.0f;
            ps[tl][s] = (_Float16)(pacc[sf][r] * f);
        }
    __syncthreads();

    half8 pf[2];
#pragma unroll
    for (int ks = 0; ks < 2; ++ks)
        pf[ks] = *(const half8*)&ps[w * 16 + l15][ks * 32 + l16 * 8];

    f32x4 acc1[8] = {};  // inter (Q S^T)
    f32x4 acc2[8] = {};  // intra (P V)
    const _Float16* Sb = S + (((size_t)blockIdx.x) << 14);
#pragma unroll
    for (int nf = 0; nf < 8; ++nf) {
#pragma unroll
        for (int kd = 0; kd < 4; ++kd) {
            half8 bf = *(const half8*)(Sb + (size_t)(nf * 16 + l15) * 128 + kd * 32 + l16 * 8);
            acc1[nf] = __builtin_amdgcn_mfma_f32_16x16x32_f16(af[kd], bf, acc1[nf], 0, 0, 0);
        }
#pragma unroll
        for (int ks = 0; ks < 2; ++ks) {
            half8 bf = *(const half8*)&vt[nf * 16 + l15][ks * 32 + l16 * 8];
            acc2[nf] = __builtin_amdgcn_mfma_f32_16x16x32_f16(pf[ks], bf, acc2[nf], 0, 0, 0);
        }
    }
#pragma unroll
    for (int nf = 0; nf < 8; ++nf)
#pragma unroll
        for (int r = 0; r < 4; ++r) {
            int tl = w * 16 + l16 * 4 + r;
            int n = nf * 16 + l15;
            size_t row = (size_t)(b * T_ + c * 64 + tl);
            float o = acc2[nf][r] + __expf(ld * (float)(tl + 1)) * acc1[nf][r];
            float g = (float)pg[row * DIM_ + h * 128 + n];
            gated[row * DIM_ + h * 128 + n] = (_Float16)(o * sigmoidf_(g));
        }
}

// ---------------------------------------------------------------------------
extern "C" void kernel_launch(void* const* d_in, const int* in_sizes, int n_in,
                              void* d_out, int out_size, void* d_ws, size_t ws_size,
                              hipStream_t stream)
{
    const float* x     = (const float*)d_in[0];
    const float* Wq    = (const float*)d_in[1];
    const float* Wk    = (const float*)d_in[2];
    const float* Wv    = (const float*)d_in[3];
    const float* Wo    = (const float*)d_in[4];
    const float* Wg    = (const float*)d_in[5];
    const float* qw    = (const float*)d_in[6];
    const float* qb    = (const float*)d_in[7];
    const float* kw    = (const float*)d_in[8];
    const float* kb    = (const float*)d_in[9];
    const float* vw    = (const float*)d_in[10];
    const float* vb    = (const float*)d_in[11];
    const float* beta  = (const float*)d_in[12];
    const float* A_log = (const float*)d_in[13];
    float* out = (float*)d_out;

    char* wsb = (char*)d_ws;
    const size_t WT  = (size_t)DIM_ * DIM_ * 2;   // f16 weight bytes (8 MB)
    const size_t SZ  = (size_t)B_ * T_ * DIM_;    // elements
    const size_t SZH = SZ * 2;                    // f16 buffer bytes (16 MB)

    _Float16* wtq = (_Float16*)(wsb + 0 * WT);    // wtq..wtg contiguous = Bt[8192][2048]
    _Float16* wtk = (_Float16*)(wsb + 1 * WT);
    _Float16* wtv = (_Float16*)(wsb + 2 * WT);
    _Float16* wtg = (_Float16*)(wsb + 3 * WT);
    _Float16* wto = (_Float16*)(wsb + 4 * WT);
    char* pbase = wsb + 5 * WT;
    _Float16* pq = (_Float16*)(pbase + 0 * SZH);
    _Float16* pk = (_Float16*)(pbase + 1 * SZH);
    _Float16* pv = (_Float16*)(pbase + 2 * SZH);
    _Float16* xh = (_Float16*)(pbase + 3 * SZH);
    _Float16* pg = (_Float16*)(pbase + 4 * SZH);
    _Float16* qh = (_Float16*)(pbase + 5 * SZH);
    _Float16* kh = (_Float16*)(pbase + 6 * SZH);
    _Float16* vh = (_Float16*)(pbase + 7 * SZH);
    _Float16* U     = pq;  // 32 MB, spans pq+pk   (both dead after convs)
    _Float16* Sst   = pv;  // 32 MB, spans pv+xh   (dead after conv_v / GEMMs)
    _Float16* gated = pq;  // 16 MB, U dead after r2

    const int M = B_ * T_;  // 4096

    cvt_f16<<<(int)(SZ / 2048), 256, 0, stream>>>(x, xh);
    dim3 tg(DIM_ / 64, DIM_ / 64);
    wconvT<<<tg, 256, 0, stream>>>(Wq, wtq, DIM_, DIM_);
    wconvT<<<tg, 256, 0, stream>>>(Wk, wtk, DIM_, DIM_);
    wconvT<<<tg, 256, 0, stream>>>(Wv, wtv, DIM_, DIM_);
    wconvT<<<tg, 256, 0, stream>>>(Wg, wtg, DIM_, DIM_);
    wconvT<<<tg, 256, 0, stream>>>(Wo, wto, DIM_, DIM_);

    // fused projections: N = 8192 (q|k|v|g), nwg = 64x32 = 2048
    gemm_f16<_Float16><<<2048, 256, 0, stream>>>(xh, wtq, pq, pk, pv, pg,
                                                 DIM_, 64, 256);

    conv_f16<<<(int)(SZ / 256), 256, 0, stream>>>(pq, qw, qb, qh, 1);
    conv_knorm<<<(B_ * T_ * H_) / 4, 256, 0, stream>>>(pk, kw, kb, kh);
    conv_f16<<<(int)(SZ / 256), 256, 0, stream>>>(pv, vw, vb, vh, 0);

    r1_kernel<<<B_ * H_ * 32, 256, 0, stream>>>(kh, vh, A_log, beta, U);
    r2_kernel<<<256, 256, 0, stream>>>(U, Sst, A_log);
    r3_kernel<<<B_ * H_ * 32, 256, 0, stream>>>(qh, kh, vh, Sst, pg, A_log, beta, gated);

    // out = gated @ Wo : nwg = 16x32 = 512
    gemm_f16<float><<<512, 256, 0, stream>>>(gated, wto, out, out, out, out,
                                             DIM_, 16, 64);
}

// Round 4
// 449.399 us; speedup vs baseline: 8.3865x; 1.1321x over previous
//
#include <hip/hip_runtime.h>
#include <math.h>

#define B_   2
#define T_   2048
#define DIM_ 2048
#define H_   16

typedef __attribute__((ext_vector_type(8))) _Float16 half8;
typedef __attribute__((ext_vector_type(4))) _Float16 half4;
typedef __attribute__((ext_vector_type(4))) float f32x4;

__device__ __forceinline__ float sigmoidf_(float x) { return 1.0f / (1.0f + __expf(-x)); }

__device__ __forceinline__ void gload16(const _Float16* g, _Float16* l) {
    __builtin_amdgcn_global_load_lds((const __attribute__((address_space(1))) void*)g,
                                     (__attribute__((address_space(3))) void*)l, 16, 0, 0);
}

// ---------------------------------------------------------------------------
// fp32 -> f16 elementwise convert (8/thread)
// ---------------------------------------------------------------------------
__global__ __launch_bounds__(256) void cvt_f16(const float* __restrict__ in,
                                               _Float16* __restrict__ out)
{
    size_t i = ((size_t)blockIdx.x * 256 + threadIdx.x) * 8;
    float4 a = *(const float4*)(in + i);
    float4 b = *(const float4*)(in + i + 4);
    half8 h;
    h[0] = (_Float16)a.x; h[1] = (_Float16)a.y; h[2] = (_Float16)a.z; h[3] = (_Float16)a.w;
    h[4] = (_Float16)b.x; h[5] = (_Float16)b.y; h[6] = (_Float16)b.z; h[7] = (_Float16)b.w;
    *(half8*)(out + i) = h;
}

// ---------------------------------------------------------------------------
// 5 weight transposes fused: W[K][N] fp32 -> Wt[N][K] f16, blockIdx.z selects.
// ---------------------------------------------------------------------------
__global__ __launch_bounds__(256) void wconvT5(const float* __restrict__ W0,
                                               const float* __restrict__ W1,
                                               const float* __restrict__ W2,
                                               const float* __restrict__ W3,
                                               const float* __restrict__ W4,
                                               _Float16* __restrict__ base)
{
    __shared__ float t[64][65];
    const int z = blockIdx.z;
    const float* W = z == 0 ? W0 : z == 1 ? W1 : z == 2 ? W2 : z == 3 ? W3 : W4;
    _Float16* Wt = base + (size_t)z * DIM_ * DIM_;
    const int c = threadIdx.x & 63;
    const int r0 = threadIdx.x >> 6;
    const int n0 = blockIdx.x * 64, k0 = blockIdx.y * 64;
#pragma unroll
    for (int i = 0; i < 16; ++i) {
        int r = i * 4 + r0;
        t[r][c] = W[(size_t)(k0 + r) * DIM_ + n0 + c];
    }
    __syncthreads();
#pragma unroll
    for (int i = 0; i < 16; ++i) {
        int r = i * 4 + r0;
        Wt[(size_t)(n0 + r) * DIM_ + k0 + c] = (_Float16)t[c][r];
    }
}

// ---------------------------------------------------------------------------
// 256x256 f16 MFMA GEMM, BK=32, 8 waves (2Mx4N), 3-buffer LDS pipeline with
// counted vmcnt (T3/T4), st_16x32 XOR swizzle (T2), setprio (T5).
// C = A[M,K] * Bt[N,K]^T ; epilogue splits N into 2048-col segments.
// ---------------------------------------------------------------------------
template <typename OT>
__global__ __launch_bounds__(512, 2) void gemm256(const _Float16* __restrict__ A,
                                                  const _Float16* __restrict__ Bt,
                                                  OT* __restrict__ C0, OT* __restrict__ C1,
                                                  OT* __restrict__ C2, OT* __restrict__ C3,
                                                  int K, int nx, int cpx)
{
    __shared__ _Float16 lds[3][2][8192];   // [buf][A|B][256 rows x 32 k-halfs]

    const int tid = threadIdx.x;           // 0..511
    const int lane = tid & 63, w = tid >> 6;
    const int wr = w >> 2, wc = w & 3;     // 2 x 4 wave grid
    const int l15 = lane & 15, l16 = lane >> 4;

    const int bid = blockIdx.x;
    const int swz = (bid & 7) * cpx + (bid >> 3);   // XCD swizzle (nwg%8==0)
    const int bm = (swz / nx) * 256, bn = (swz % nx) * 256;

    // staging: linear LDS dest, pre-swizzled global source.
    // F (halfs) = (ld*512+tid)*8 ; F' = F ^ (((F>>8)&1)<<4) ; row=F'>>5 col=F'&31
    int ldsoff[2];
    const _Float16* Asrc[2];
    const _Float16* Bsrc[2];
#pragma unroll
    for (int ld = 0; ld < 2; ++ld) {
        int F = (ld * 512 + tid) * 8;
        ldsoff[ld] = F;
        int Fp = F ^ (((F >> 8) & 1) << 4);
        int row = Fp >> 5, col = Fp & 31;
        Asrc[ld] = A + (size_t)(bm + row) * K + col;
        Bsrc[ld] = Bt + (size_t)(bn + row) * K + col;
    }

    // fragment read offsets (halfs), swizzled with the same XOR
    int aoff[8], boff[4];
#pragma unroll
    for (int m = 0; m < 8; ++m) {
        int row = wr * 128 + m * 16 + l15;
        aoff[m] = row * 32 + ((l16 * 8) ^ (((row >> 3) & 1) << 4));
    }
#pragma unroll
    for (int n = 0; n < 4; ++n) {
        int row = wc * 64 + n * 16 + l15;
        boff[n] = row * 32 + ((l16 * 8) ^ (((row >> 3) & 1) << 4));
    }

    f32x4 acc[8][4] = {};
    const int nt = K >> 5;

#define STAGE256(kt, buf) do {                                        \
        gload16(Asrc[0] + (kt) * 32, &lds[buf][0][ldsoff[0]]);        \
        gload16(Asrc[1] + (kt) * 32, &lds[buf][0][ldsoff[1]]);        \
        gload16(Bsrc[0] + (kt) * 32, &lds[buf][1][ldsoff[0]]);        \
        gload16(Bsrc[1] + (kt) * 32, &lds[buf][1][ldsoff[1]]);        \
    } while (0)

    STAGE256(0, 0);
    STAGE256(1, 1);
    asm volatile("s_waitcnt vmcnt(4)" ::: "memory");   // tile 0 landed (own)
    __builtin_amdgcn_s_barrier();                      // all waves' tile 0 landed
    __builtin_amdgcn_sched_barrier(0);

    for (int t = 0; t < nt; ++t) {
        const int cb = t % 3;
        if (t + 2 < nt) STAGE256(t + 2, (t + 2) % 3);

        const _Float16* Al = lds[cb][0];
        const _Float16* Bl = lds[cb][1];
        half8 af[8], bf[4];
#pragma unroll
        for (int m = 0; m < 8; ++m) af[m] = *(const half8*)(Al + aoff[m]);
#pragma unroll
        for (int n = 0; n < 4; ++n) bf[n] = *(const half8*)(Bl + boff[n]);

        __builtin_amdgcn_s_setprio(1);
#pragma unroll
        for (int m = 0; m < 8; ++m)
#pragma unroll
            for (int n = 0; n < 4; ++n)
                acc[m][n] = __builtin_amdgcn_mfma_f32_16x16x32_f16(af[m], bf[n], acc[m][n], 0, 0, 0);
        __builtin_amdgcn_s_setprio(0);

        __builtin_amdgcn_sched_barrier(0);
        if (t + 2 < nt) {
            asm volatile("s_waitcnt vmcnt(4)" ::: "memory");  // tile t+1 landed
        } else {
            asm volatile("s_waitcnt vmcnt(0)" ::: "memory");  // tail drain
        }
        __builtin_amdgcn_s_barrier();
        __builtin_amdgcn_sched_barrier(0);
    }
#undef STAGE256

    const int sel = bn >> 11;
    OT* __restrict__ C = sel == 0 ? C0 : sel == 1 ? C1 : sel == 2 ? C2 : C3;
    const int ccb = (bn & 2047) + wc * 64;
    const int crb = bm + wr * 128;
#pragma unroll
    for (int m = 0; m < 8; ++m)
#pragma unroll
        for (int n = 0; n < 4; ++n)
#pragma unroll
            for (int r = 0; r < 4; ++r)
                C[(size_t)(crb + m * 16 + l16 * 4 + r) * 2048 + ccb + n * 16 + l15] =
                    (OT)acc[m][n][r];
}

// ---------------------------------------------------------------------------
// 128x128 m97-structure GEMM (kept for the Wo matmul: 512 tiles -> full grid)
// ---------------------------------------------------------------------------
template <typename OT>
__global__ __launch_bounds__(256) void gemm_f16(const _Float16* __restrict__ A,
                                                const _Float16* __restrict__ Bt,
                                                OT* __restrict__ C0, OT* __restrict__ C1,
                                                OT* __restrict__ C2, OT* __restrict__ C3,
                                                int K, int nx, int cpx)
{
    __shared__ _Float16 As[128 * 32];
    __shared__ _Float16 Bs[128 * 32];
    const int tid = threadIdx.x;
    const int lane = tid & 63, w = tid >> 6;
    const int wr = w >> 1, wc = w & 1;

    const int bid = blockIdx.x;
    const int swz = (bid & 7) * cpx + (bid >> 3);
    const int bx = swz % nx, by = swz / nx;
    const int bm = by * 128, bn = bx * 128;

    const int l15 = lane & 15, l16 = lane >> 4;

    const _Float16* Ag = A + (size_t)(bm + (tid >> 2)) * K + (tid & 3) * 8;
    const _Float16* Bg = Bt + (size_t)(bn + (tid >> 2)) * K + (tid & 3) * 8;
    _Float16* AsD0 = As + w * 512;
    _Float16* AsD1 = As + 2048 + w * 512;
    _Float16* BsD0 = Bs + w * 512;
    _Float16* BsD1 = Bs + 2048 + w * 512;
    const size_t rowoff = (size_t)64 * K;

    f32x4 acc[4][4] = {};

    for (int k0 = 0; k0 < K; k0 += 32) {
        __syncthreads();
        gload16(Ag + k0, AsD0);
        gload16(Ag + rowoff + k0, AsD1);
        gload16(Bg + k0, BsD0);
        gload16(Bg + rowoff + k0, BsD1);
        __syncthreads();
        half8 af[4], bf[4];
#pragma unroll
        for (int i = 0; i < 4; ++i)
            af[i] = *(const half8*)(As + (wr * 64 + i * 16 + l15) * 32 + l16 * 8);
#pragma unroll
        for (int j = 0; j < 4; ++j)
            bf[j] = *(const half8*)(Bs + (wc * 64 + j * 16 + l15) * 32 + l16 * 8);
#pragma unroll
        for (int i = 0; i < 4; ++i)
#pragma unroll
            for (int j = 0; j < 4; ++j)
                acc[i][j] = __builtin_amdgcn_mfma_f32_16x16x32_f16(af[i], bf[j], acc[i][j], 0, 0, 0);
    }

    const int sel = bn >> 11;
    OT* __restrict__ C = sel == 0 ? C0 : sel == 1 ? C1 : sel == 2 ? C2 : C3;
    const int crow = bm + wr * 64 + l16 * 4;
    const int ccol = (bn & 2047) + wc * 64 + l15;
#pragma unroll
    for (int i = 0; i < 4; ++i)
#pragma unroll
        for (int j = 0; j < 4; ++j)
#pragma unroll
            for (int r = 0; r < 4; ++r)
                C[(size_t)(crow + i * 16 + r) * 2048 + ccol + j * 16] = (OT)acc[i][j][r];
}

// ---------------------------------------------------------------------------
// Depthwise causal conv K=4 + bias (+silu), f16 in/out, fp32 math.
// ---------------------------------------------------------------------------
__global__ __launch_bounds__(256) void conv_f16(const _Float16* __restrict__ xin,
                                                const float* __restrict__ w,
                                                const float* __restrict__ bias,
                                                _Float16* __restrict__ y, int act)
{
    size_t idx = (size_t)blockIdx.x * 256 + threadIdx.x;
    int cc = (int)(idx & (DIM_ - 1));
    int t = (int)((idx >> 11) & (T_ - 1));
    int b = (int)(idx >> 22);
    float acc = bias[cc];
    const _Float16* xc = xin + (size_t)b * T_ * DIM_ + cc;
#pragma unroll
    for (int j = 0; j < 4; ++j) {
        int ts = t - 3 + j;
        if (ts >= 0) acc += (float)xc[(size_t)ts * DIM_] * w[cc * 4 + j];
    }
    if (act) acc = acc * sigmoidf_(acc);
    y[idx] = (_Float16)acc;
}

// ---------------------------------------------------------------------------
// conv_k + silu + L2-normalize fused: one wave per (b,t,h) row, 2 ch/lane.
// ---------------------------------------------------------------------------
__global__ __launch_bounds__(256) void conv_knorm(const _Float16* __restrict__ xin,
                                                  const float* __restrict__ w,
                                                  const float* __restrict__ bias,
                                                  _Float16* __restrict__ kh)
{
    int lane = threadIdx.x & 63, wv = threadIdx.x >> 6;
    size_t r = (size_t)blockIdx.x * 4 + wv;   // (b*T+t)*H + h
    int h = (int)(r & 15);
    size_t gr = r >> 4;                       // b*T + t
    int t = (int)(gr & (T_ - 1));
    int c0 = h * 128 + lane * 2;

    float a0 = bias[c0], a1 = bias[c0 + 1];
#pragma unroll
    for (int j = 0; j < 4; ++j) {
        int ts = t - 3 + j;
        if (ts >= 0) {
            const _Float16* p = xin + (gr - 3 + j) * DIM_ + c0;
            a0 += (float)p[0] * w[c0 * 4 + j];
            a1 += (float)p[1] * w[(c0 + 1) * 4 + j];
        }
    }
    a0 = a0 * sigmoidf_(a0);
    a1 = a1 * sigmoidf_(a1);
    float ss = a0 * a0 + a1 * a1;
#pragma unroll
    for (int off = 1; off < 64; off <<= 1) ss += __shfl_xor(ss, off);
    float sc = 1.0f / fmaxf(sqrtf(ss), 1e-12f);
    kh[gr * DIM_ + c0]     = (_Float16)(a0 * sc);
    kh[gr * DIM_ + c0 + 1] = (_Float16)(a1 * sc);
}

// ---------------------------------------------------------------------------
// R1: per (bh, chunk) U_c = sum_s bet*decay^(63-s) * v_s k_s^T  (128x128 f16)
// ---------------------------------------------------------------------------
__global__ __launch_bounds__(256) void r1_kernel(const _Float16* __restrict__ kh,
                                                 const _Float16* __restrict__ vh,
                                                 const float* __restrict__ A_log,
                                                 const float* __restrict__ beta,
                                                 _Float16* __restrict__ U)
{
    const int c = blockIdx.x & 31, bh = blockIdx.x >> 5;
    const int h = bh & 15, b = bh >> 4;
    const float decay = sigmoidf_(A_log[h]);
    const float bet = sigmoidf_(beta[h]);
    const float ld = logf(decay);

    __shared__ _Float16 kt[128][72];
    __shared__ _Float16 vt[128][72];

    const int tid = threadIdx.x;
    const size_t base = ((size_t)(b * T_ + c * 64) * H_ + h) * 128;
    for (int rep = 0; rep < 32; ++rep) {
        int idx = rep * 256 + tid;
        int s = idx >> 7, i = idx & 127;
        float kv = (float)kh[base + (size_t)s * DIM_ + i];
        float vv = (float)vh[base + (size_t)s * DIM_ + i];
        kt[i][s] = (_Float16)kv;
        vt[i][s] = (_Float16)(bet * __expf(ld * (float)(63 - s)) * vv);
    }
    __syncthreads();

    const int lane = tid & 63, w = tid >> 6;
    const int l15 = lane & 15, l16 = lane >> 4;
    f32x4 acc[2][8] = {};
#pragma unroll
    for (int ks = 0; ks < 2; ++ks) {
        half8 a0 = *(const half8*)&vt[w * 32 + l15][ks * 32 + l16 * 8];
        half8 a1 = *(const half8*)&vt[w * 32 + 16 + l15][ks * 32 + l16 * 8];
#pragma unroll
        for (int fj = 0; fj < 8; ++fj) {
            half8 bf = *(const half8*)&kt[fj * 16 + l15][ks * 32 + l16 * 8];
            acc[0][fj] = __builtin_amdgcn_mfma_f32_16x16x32_f16(a0, bf, acc[0][fj], 0, 0, 0);
            acc[1][fj] = __builtin_amdgcn_mfma_f32_16x16x32_f16(a1, bf, acc[1][fj], 0, 0, 0);
        }
    }
    _Float16* Ub = U + (((size_t)blockIdx.x) << 14);
#pragma unroll
    for (int fi = 0; fi < 2; ++fi)
#pragma unroll
        for (int fj = 0; fj < 8; ++fj)
#pragma unroll
            for (int r = 0; r < 4; ++r) {
                int i = w * 32 + fi * 16 + l16 * 4 + r;
                int j = fj * 16 + l15;
                Ub[i * 128 + j] = (_Float16)acc[fi][fj][r];
            }
}

// ---------------------------------------------------------------------------
// R2: chunk-boundary state scan, parallel over (bh, 2048-elem slices).
// ---------------------------------------------------------------------------
__global__ __launch_bounds__(256) void r2_kernel(const _Float16* __restrict__ U,
                                                 _Float16* __restrict__ S,
                                                 const float* __restrict__ A_log)
{
    const int blk = blockIdx.x;
    const int bh = blk >> 3, part = blk & 7, h = bh & 15;
    const float decay = sigmoidf_(A_log[h]);
    const float d64 = __expf(64.0f * logf(decay));
    const size_t base = ((size_t)bh << 19) + (size_t)part * 2048 + (size_t)threadIdx.x * 8;
    const half8* Up = (const half8*)(U + base);
    half8* Sp = (half8*)(S + base);

    float st[8] = {0, 0, 0, 0, 0, 0, 0, 0};
    half8 n0 = Up[0];
    half8 n1 = Up[2048];
    for (int c = 0; c < 32; ++c) {
        half8 cur = n0;
        n0 = n1;
        if (c + 2 < 32) n1 = Up[(size_t)(c + 2) * 2048];
        half8 so;
#pragma unroll
        for (int i = 0; i < 8; ++i) {
            so[i] = (_Float16)st[i];
            st[i] = d64 * st[i] + (float)cur[i];
        }
        Sp[(size_t)c * 2048] = so;
    }
}

// ---------------------------------------------------------------------------
// R3: per (bh, chunk): out = mask(QK^T)V + rowscale(Q S^T); gate fused.
// ---------------------------------------------------------------------------
__global__ __launch_bounds__(256) void r3_kernel(const _Float16* __restrict__ qh,
                                                 const _Float16* __restrict__ kh,
                                                 const _Float16* __restrict__ vh,
                                                 const _Float16* __restrict__ S,
                                                 const _Float16* __restrict__ pg,
                                                 const float* __restrict__ A_log,
                                                 const float* __restrict__ beta,
                                                 _Float16* __restrict__ gated)
{
    const int c = blockIdx.x & 31, bh = blockIdx.x >> 5;
    const int h = bh & 15, b = bh >> 4;
    const float decay = sigmoidf_(A_log[h]);
    const float bet = sigmoidf_(beta[h]);
    const float ld = logf(decay);

    __shared__ _Float16 vt[128][72];
    __shared__ _Float16 ps[64][72];

    const int tid = threadIdx.x;
    const size_t base = ((size_t)(b * T_ + c * 64) * H_ + h) * 128;
    for (int rep = 0; rep < 32; ++rep) {
        int idx = rep * 256 + tid;
        int s = idx >> 7, n = idx & 127;
        vt[n][s] = vh[base + (size_t)s * DIM_ + n];
    }
    __syncthreads();

    const int lane = tid & 63, w = tid >> 6;
    const int l15 = lane & 15, l16 = lane >> 4;

    const _Float16* qrow = qh + base + (size_t)(w * 16 + l15) * DIM_;
    half8 af[4];
#pragma unroll
    for (int kd = 0; kd < 4; ++kd) af[kd] = *(const half8*)(qrow + kd * 32 + l16 * 8);

    f32x4 pacc[4] = {};
    const _Float16* kb = kh + base;
#pragma unroll
    for (int sf = 0; sf < 4; ++sf)
#pragma unroll
        for (int kd = 0; kd < 4; ++kd) {
            half8 bf = *(const half8*)(kb + (size_t)(sf * 16 + l15) * DIM_ + kd * 32 + l16 * 8);
            pacc[sf] = __builtin_amdgcn_mfma_f32_16x16x32_f16(af[kd], bf, pacc[sf], 0, 0, 0);
        }
#pragma unroll
    for (int sf = 0; sf < 4; ++sf)
#pragma unroll
        for (int r = 0; r < 4; ++r) {
            int tl = w * 16 + l16 * 4 + r;
            int s = sf * 16 + l15;
            float f = (s <= tl) ? bet * __expf(ld * (float)(tl - s)) : 0.0f;
            ps[tl][s] = (_Float16)(pacc[sf][r] * f);
        }
    __syncthreads();

    half8 pf[2];
#pragma unroll
    for (int ks = 0; ks < 2; ++ks)
        pf[ks] = *(const half8*)&ps[w * 16 + l15][ks * 32 + l16 * 8];

    f32x4 acc1[8] = {};
    f32x4 acc2[8] = {};
    const _Float16* Sb = S + (((size_t)blockIdx.x) << 14);
#pragma unroll
    for (int nf = 0; nf < 8; ++nf) {
#pragma unroll
        for (int kd = 0; kd < 4; ++kd) {
            half8 bf = *(const half8*)(Sb + (size_t)(nf * 16 + l15) * 128 + kd * 32 + l16 * 8);
            acc1[nf] = __builtin_amdgcn_mfma_f32_16x16x32_f16(af[kd], bf, acc1[nf], 0, 0, 0);
        }
#pragma unroll
        for (int ks = 0; ks < 2; ++ks) {
            half8 bf = *(const half8*)&vt[nf * 16 + l15][ks * 32 + l16 * 8];
            acc2[nf] = __builtin_amdgcn_mfma_f32_16x16x32_f16(pf[ks], bf, acc2[nf], 0, 0, 0);
        }
    }
#pragma unroll
    for (int nf = 0; nf < 8; ++nf)
#pragma unroll
        for (int r = 0; r < 4; ++r) {
            int tl = w * 16 + l16 * 4 + r;
            int n = nf * 16 + l15;
            size_t row = (size_t)(b * T_ + c * 64 + tl);
            float o = acc2[nf][r] + __expf(ld * (float)(tl + 1)) * acc1[nf][r];
            float g = (float)pg[row * DIM_ + h * 128 + n];
            gated[row * DIM_ + h * 128 + n] = (_Float16)(o * sigmoidf_(g));
        }
}

// ---------------------------------------------------------------------------
extern "C" void kernel_launch(void* const* d_in, const int* in_sizes, int n_in,
                              void* d_out, int out_size, void* d_ws, size_t ws_size,
                              hipStream_t stream)
{
    const float* x     = (const float*)d_in[0];
    const float* Wq    = (const float*)d_in[1];
    const float* Wk    = (const float*)d_in[2];
    const float* Wv    = (const float*)d_in[3];
    const float* Wo    = (const float*)d_in[4];
    const float* Wg    = (const float*)d_in[5];
    const float* qw    = (const float*)d_in[6];
    const float* qb    = (const float*)d_in[7];
    const float* kw    = (const float*)d_in[8];
    const float* kb    = (const float*)d_in[9];
    const float* vw    = (const float*)d_in[10];
    const float* vb    = (const float*)d_in[11];
    const float* beta  = (const float*)d_in[12];
    const float* A_log = (const float*)d_in[13];
    float* out = (float*)d_out;

    char* wsb = (char*)d_ws;
    const size_t WT  = (size_t)DIM_ * DIM_ * 2;
    const size_t SZ  = (size_t)B_ * T_ * DIM_;
    const size_t SZH = SZ * 2;

    _Float16* wtq = (_Float16*)(wsb + 0 * WT);    // wtq..wtg contiguous = Bt[8192][2048]
    _Float16* wto = (_Float16*)(wsb + 4 * WT);
    char* pbase = wsb + 5 * WT;
    _Float16* pq = (_Float16*)(pbase + 0 * SZH);
    _Float16* pk = (_Float16*)(pbase + 1 * SZH);
    _Float16* pv = (_Float16*)(pbase + 2 * SZH);
    _Float16* xh = (_Float16*)(pbase + 3 * SZH);
    _Float16* pg = (_Float16*)(pbase + 4 * SZH);
    _Float16* qh = (_Float16*)(pbase + 5 * SZH);
    _Float16* kh = (_Float16*)(pbase + 6 * SZH);
    _Float16* vh = (_Float16*)(pbase + 7 * SZH);
    _Float16* U     = pq;  // 32 MB, spans pq+pk (dead after convs)
    _Float16* Sst   = pv;  // 32 MB, spans pv+xh (dead after conv_v / GEMMs)
    _Float16* gated = pq;  // 16 MB, U dead after r2

    cvt_f16<<<(int)(SZ / 2048), 256, 0, stream>>>(x, xh);
    wconvT5<<<dim3(32, 32, 5), 256, 0, stream>>>(Wq, Wk, Wv, Wg, Wo, wtq);

    // fused projections: M=4096, N=8192 (q|k|v|g): 16x32 = 512 tiles of 256^2
    gemm256<_Float16><<<512, 512, 0, stream>>>(xh, wtq, pq, pk, pv, pg,
                                               DIM_, 32, 64);

    conv_f16<<<(int)(SZ / 256), 256, 0, stream>>>(pq, qw, qb, qh, 1);
    conv_knorm<<<(B_ * T_ * H_) / 4, 256, 0, stream>>>(pk, kw, kb, kh);
    conv_f16<<<(int)(SZ / 256), 256, 0, stream>>>(pv, vw, vb, vh, 0);

    r1_kernel<<<B_ * H_ * 32, 256, 0, stream>>>(kh, vh, A_log, beta, U);
    r2_kernel<<<256, 256, 0, stream>>>(U, Sst, A_log);
    r3_kernel<<<B_ * H_ * 32, 256, 0, stream>>>(qh, kh, vh, Sst, pg, A_log, beta, gated);

    // out = gated @ Wo : 128^2 tiles, 16x32 = 512 WGs
    gemm_f16<float><<<512, 256, 0, stream>>>(gated, wto, out, out, out, out,
                                             DIM_, 16, 64);
}

// Round 5
// 435.572 us; speedup vs baseline: 8.6527x; 1.0317x over previous
//
#include <hip/hip_runtime.h>
#include <math.h>

#define B_   2
#define T_   2048
#define DIM_ 2048
#define H_   16

typedef __attribute__((ext_vector_type(8))) _Float16 half8;
typedef __attribute__((ext_vector_type(4))) _Float16 half4;
typedef __attribute__((ext_vector_type(4))) float f32x4;

__device__ __forceinline__ float sigmoidf_(float x) { return 1.0f / (1.0f + __expf(-x)); }

__device__ __forceinline__ void gload16(const _Float16* g, _Float16* l) {
    __builtin_amdgcn_global_load_lds((const __attribute__((address_space(1))) void*)g,
                                     (__attribute__((address_space(3))) void*)l, 16, 0, 0);
}

// ---------------------------------------------------------------------------
// fp32 -> f16 elementwise convert (8/thread)
// ---------------------------------------------------------------------------
__global__ __launch_bounds__(256) void cvt_f16(const float* __restrict__ in,
                                               _Float16* __restrict__ out)
{
    size_t i = ((size_t)blockIdx.x * 256 + threadIdx.x) * 8;
    float4 a = *(const float4*)(in + i);
    float4 b = *(const float4*)(in + i + 4);
    half8 h;
    h[0] = (_Float16)a.x; h[1] = (_Float16)a.y; h[2] = (_Float16)a.z; h[3] = (_Float16)a.w;
    h[4] = (_Float16)b.x; h[5] = (_Float16)b.y; h[6] = (_Float16)b.z; h[7] = (_Float16)b.w;
    *(half8*)(out + i) = h;
}

// ---------------------------------------------------------------------------
// 5 weight transposes fused: W[K][N] fp32 -> Wt[N][K] f16, blockIdx.z selects.
// ---------------------------------------------------------------------------
__global__ __launch_bounds__(256) void wconvT5(const float* __restrict__ W0,
                                               const float* __restrict__ W1,
                                               const float* __restrict__ W2,
                                               const float* __restrict__ W3,
                                               const float* __restrict__ W4,
                                               _Float16* __restrict__ base)
{
    __shared__ float t[64][65];
    const int z = blockIdx.z;
    const float* W = z == 0 ? W0 : z == 1 ? W1 : z == 2 ? W2 : z == 3 ? W3 : W4;
    _Float16* Wt = base + (size_t)z * DIM_ * DIM_;
    const int c = threadIdx.x & 63;
    const int r0 = threadIdx.x >> 6;
    const int n0 = blockIdx.x * 64, k0 = blockIdx.y * 64;
#pragma unroll
    for (int i = 0; i < 16; ++i) {
        int r = i * 4 + r0;
        t[r][c] = W[(size_t)(k0 + r) * DIM_ + n0 + c];
    }
    __syncthreads();
#pragma unroll
    for (int i = 0; i < 16; ++i) {
        int r = i * 4 + r0;
        Wt[(size_t)(n0 + r) * DIM_ + k0 + c] = (_Float16)t[c][r];
    }
}

// ---------------------------------------------------------------------------
// Pipelined f16 MFMA GEMM: BM x 256 tile, BK=32, 8 waves (2Mx4N), 3-buffer
// LDS with counted vmcnt (T3/T4), st_16x32 XOR swizzle (T2), 2-phase K-tile
// split with setprio (T5). C = A[M,K] * Bt[N,K]^T, N split into 2048-col segs.
// ---------------------------------------------------------------------------
template <int BM, typename OT>
__global__ __launch_bounds__(512, 2) void gemm256(const _Float16* __restrict__ A,
                                                  const _Float16* __restrict__ Bt,
                                                  OT* __restrict__ C0, OT* __restrict__ C1,
                                                  OT* __restrict__ C2, OT* __restrict__ C3,
                                                  int K, int nx, int cpx)
{
    constexpr int BN = 256;
    constexpr int LA = BM / 128;        // A stage loads per thread
    constexpr int LB = BN / 128;        // B stage loads per thread
    constexpr int MF = BM / 32;         // A fragments per wave
    __shared__ _Float16 lds[3][(BM + BN) * 32];

    const int tid = threadIdx.x;
    const int lane = tid & 63, w = tid >> 6;
    const int wr = w >> 2, wc = w & 3;
    const int l15 = lane & 15, l16 = lane >> 4;

    const int bid = blockIdx.x;
    const int swz = (bid & 7) * cpx + (bid >> 3);   // XCD swizzle (nwg%8==0)
    const int bm = (swz / nx) * BM, bn = (swz % nx) * BN;

    // staging: linear LDS dest (base + lane*16B), pre-swizzled global source.
    int offA[LA], offB[LB];
    const _Float16* Asrc[LA];
    const _Float16* Bsrc[LB];
#pragma unroll
    for (int ld = 0; ld < LA; ++ld) {
        int F = (ld * 512 + tid) * 8;
        offA[ld] = F;
        int Fp = F ^ (((F >> 8) & 1) << 4);
        Asrc[ld] = A + (size_t)(bm + (Fp >> 5)) * K + (Fp & 31);
    }
#pragma unroll
    for (int ld = 0; ld < LB; ++ld) {
        int F = (ld * 512 + tid) * 8;
        offB[ld] = BM * 32 + F;
        int Fp = F ^ (((F >> 8) & 1) << 4);
        Bsrc[ld] = Bt + (size_t)(bn + (Fp >> 5)) * K + (Fp & 31);
    }

    // fragment read offsets, same XOR swizzle
    int aoff[MF], boff[4];
#pragma unroll
    for (int m = 0; m < MF; ++m) {
        int row = wr * (BM / 2) + m * 16 + l15;
        aoff[m] = row * 32 + ((l16 * 8) ^ (((row >> 3) & 1) << 4));
    }
#pragma unroll
    for (int n = 0; n < 4; ++n) {
        int row = wc * 64 + n * 16 + l15;
        boff[n] = BM * 32 + row * 32 + ((l16 * 8) ^ (((row >> 3) & 1) << 4));
    }

    f32x4 acc[MF][4] = {};
    const int nt = K >> 5;

#define STAGEA(kt, buf) do { _Pragma("unroll")                                 \
        for (int ld_ = 0; ld_ < LA; ++ld_)                                     \
            gload16(Asrc[ld_] + (kt) * 32, &lds[buf][offA[ld_]]); } while (0)
#define STAGEB(kt, buf) do { _Pragma("unroll")                                 \
        for (int ld_ = 0; ld_ < LB; ++ld_)                                     \
            gload16(Bsrc[ld_] + (kt) * 32, &lds[buf][offB[ld_]]); } while (0)
#define VMCNT_STEADY() do { if constexpr (LA + LB == 4)                        \
            asm volatile("s_waitcnt vmcnt(4)" ::: "memory");                   \
        else asm volatile("s_waitcnt vmcnt(3)" ::: "memory"); } while (0)

    STAGEA(0, 0); STAGEB(0, 0);
    STAGEA(1, 1); STAGEB(1, 1);
    VMCNT_STEADY();                        // tile 0 landed (own loads)
    __builtin_amdgcn_s_barrier();          // all waves' tile 0 landed
    __builtin_amdgcn_sched_barrier(0);

    for (int t = 0; t < nt; ++t) {
        const int cb = t % 3, nb = (t + 2) % 3;
        const _Float16* L = lds[cb];
        const bool pf = (t + 2 < nt);

        // ---- phase A: A-frags + B-frags 0,1 ; prefetch next-next A ----
        half8 af[MF], bf0, bf1;
#pragma unroll
        for (int m = 0; m < MF; ++m) af[m] = *(const half8*)(L + aoff[m]);
        bf0 = *(const half8*)(L + boff[0]);
        bf1 = *(const half8*)(L + boff[1]);
        if (pf) STAGEA(t + 2, nb);
        __builtin_amdgcn_s_barrier();
        __builtin_amdgcn_sched_barrier(0);
        __builtin_amdgcn_s_setprio(1);
#pragma unroll
        for (int m = 0; m < MF; ++m) {
            acc[m][0] = __builtin_amdgcn_mfma_f32_16x16x32_f16(af[m], bf0, acc[m][0], 0, 0, 0);
            acc[m][1] = __builtin_amdgcn_mfma_f32_16x16x32_f16(af[m], bf1, acc[m][1], 0, 0, 0);
        }
        __builtin_amdgcn_s_setprio(0);
        __builtin_amdgcn_sched_barrier(0);
        __builtin_amdgcn_s_barrier();

        // ---- phase B: B-frags 2,3 ; prefetch next-next B ----
        half8 bf2, bf3;
        bf2 = *(const half8*)(L + boff[2]);
        bf3 = *(const half8*)(L + boff[3]);
        if (pf) STAGEB(t + 2, nb);
        __builtin_amdgcn_s_barrier();
        __builtin_amdgcn_sched_barrier(0);
        __builtin_amdgcn_s_setprio(1);
#pragma unroll
        for (int m = 0; m < MF; ++m) {
            acc[m][2] = __builtin_amdgcn_mfma_f32_16x16x32_f16(af[m], bf2, acc[m][2], 0, 0, 0);
            acc[m][3] = __builtin_amdgcn_mfma_f32_16x16x32_f16(af[m], bf3, acc[m][3], 0, 0, 0);
        }
        __builtin_amdgcn_s_setprio(0);
        __builtin_amdgcn_sched_barrier(0);

        // ---- end of K-tile: tile t+1 must be landed chip-wide ----
        if (pf) VMCNT_STEADY();
        else    asm volatile("s_waitcnt vmcnt(0)" ::: "memory");
        __builtin_amdgcn_s_barrier();
        __builtin_amdgcn_sched_barrier(0);
    }
#undef STAGEA
#undef STAGEB
#undef VMCNT_STEADY

    const int sel = bn >> 11;
    OT* __restrict__ C = sel == 0 ? C0 : sel == 1 ? C1 : sel == 2 ? C2 : C3;
    const int ccb = (bn & 2047) + wc * 64;
    const int crb = bm + wr * (BM / 2);
#pragma unroll
    for (int m = 0; m < MF; ++m)
#pragma unroll
        for (int n = 0; n < 4; ++n)
#pragma unroll
            for (int r = 0; r < 4; ++r)
                C[(size_t)(crb + m * 16 + l16 * 4 + r) * 2048 + ccb + n * 16 + l15] =
                    (OT)acc[m][n][r];
}

// ---------------------------------------------------------------------------
// Depthwise causal conv K=4 + bias (+silu). blockIdx.y: 0 = q(silu), 1 = v.
// ---------------------------------------------------------------------------
__global__ __launch_bounds__(256) void conv_qv(const _Float16* __restrict__ qin,
                                               const _Float16* __restrict__ vin,
                                               const float* __restrict__ qw,
                                               const float* __restrict__ qb,
                                               const float* __restrict__ vw,
                                               const float* __restrict__ vb,
                                               _Float16* __restrict__ qo,
                                               _Float16* __restrict__ vo)
{
    const int act = blockIdx.y == 0;
    const _Float16* xin = act ? qin : vin;
    const float* w = act ? qw : vw;
    const float* bias = act ? qb : vb;
    _Float16* y = act ? qo : vo;

    size_t idx = (size_t)blockIdx.x * 256 + threadIdx.x;
    int cc = (int)(idx & (DIM_ - 1));
    int t = (int)((idx >> 11) & (T_ - 1));
    int b = (int)(idx >> 22);
    float acc = bias[cc];
    const _Float16* xc = xin + (size_t)b * T_ * DIM_ + cc;
#pragma unroll
    for (int j = 0; j < 4; ++j) {
        int ts = t - 3 + j;
        if (ts >= 0) acc += (float)xc[(size_t)ts * DIM_] * w[cc * 4 + j];
    }
    if (act) acc = acc * sigmoidf_(acc);
    y[idx] = (_Float16)acc;
}

// ---------------------------------------------------------------------------
// conv_k + silu + L2-normalize fused: one wave per (b,t,h) row, 2 ch/lane.
// ---------------------------------------------------------------------------
__global__ __launch_bounds__(256) void conv_knorm(const _Float16* __restrict__ xin,
                                                  const float* __restrict__ w,
                                                  const float* __restrict__ bias,
                                                  _Float16* __restrict__ kh)
{
    int lane = threadIdx.x & 63, wv = threadIdx.x >> 6;
    size_t r = (size_t)blockIdx.x * 4 + wv;   // (b*T+t)*H + h
    int h = (int)(r & 15);
    size_t gr = r >> 4;                       // b*T + t
    int t = (int)(gr & (T_ - 1));
    int c0 = h * 128 + lane * 2;

    float a0 = bias[c0], a1 = bias[c0 + 1];
#pragma unroll
    for (int j = 0; j < 4; ++j) {
        int ts = t - 3 + j;
        if (ts >= 0) {
            const _Float16* p = xin + (gr - 3 + j) * DIM_ + c0;
            a0 += (float)p[0] * w[c0 * 4 + j];
            a1 += (float)p[1] * w[(c0 + 1) * 4 + j];
        }
    }
    a0 = a0 * sigmoidf_(a0);
    a1 = a1 * sigmoidf_(a1);
    float ss = a0 * a0 + a1 * a1;
#pragma unroll
    for (int off = 1; off < 64; off <<= 1) ss += __shfl_xor(ss, off);
    float sc = 1.0f / fmaxf(sqrtf(ss), 1e-12f);
    kh[gr * DIM_ + c0]     = (_Float16)(a0 * sc);
    kh[gr * DIM_ + c0 + 1] = (_Float16)(a1 * sc);
}

// ---------------------------------------------------------------------------
// R1: per (bh, chunk) U_c = sum_s bet*decay^(63-s) * v_s k_s^T  (128x128 f16)
// ---------------------------------------------------------------------------
__global__ __launch_bounds__(256) void r1_kernel(const _Float16* __restrict__ kh,
                                                 const _Float16* __restrict__ vh,
                                                 const float* __restrict__ A_log,
                                                 const float* __restrict__ beta,
                                                 _Float16* __restrict__ U)
{
    const int c = blockIdx.x & 31, bh = blockIdx.x >> 5;
    const int h = bh & 15, b = bh >> 4;
    const float decay = sigmoidf_(A_log[h]);
    const float bet = sigmoidf_(beta[h]);
    const float ld = logf(decay);

    __shared__ _Float16 kt[128][72];
    __shared__ _Float16 vt[128][72];

    const int tid = threadIdx.x;
    const size_t base = ((size_t)(b * T_ + c * 64) * H_ + h) * 128;
    for (int rep = 0; rep < 32; ++rep) {
        int idx = rep * 256 + tid;
        int s = idx >> 7, i = idx & 127;
        float kv = (float)kh[base + (size_t)s * DIM_ + i];
        float vv = (float)vh[base + (size_t)s * DIM_ + i];
        kt[i][s] = (_Float16)kv;
        vt[i][s] = (_Float16)(bet * __expf(ld * (float)(63 - s)) * vv);
    }
    __syncthreads();

    const int lane = tid & 63, w = tid >> 6;
    const int l15 = lane & 15, l16 = lane >> 4;
    f32x4 acc[2][8] = {};
#pragma unroll
    for (int ks = 0; ks < 2; ++ks) {
        half8 a0 = *(const half8*)&vt[w * 32 + l15][ks * 32 + l16 * 8];
        half8 a1 = *(const half8*)&vt[w * 32 + 16 + l15][ks * 32 + l16 * 8];
#pragma unroll
        for (int fj = 0; fj < 8; ++fj) {
            half8 bf = *(const half8*)&kt[fj * 16 + l15][ks * 32 + l16 * 8];
            acc[0][fj] = __builtin_amdgcn_mfma_f32_16x16x32_f16(a0, bf, acc[0][fj], 0, 0, 0);
            acc[1][fj] = __builtin_amdgcn_mfma_f32_16x16x32_f16(a1, bf, acc[1][fj], 0, 0, 0);
        }
    }
    _Float16* Ub = U + (((size_t)blockIdx.x) << 14);
#pragma unroll
    for (int fi = 0; fi < 2; ++fi)
#pragma unroll
        for (int fj = 0; fj < 8; ++fj)
#pragma unroll
            for (int r = 0; r < 4; ++r) {
                int i = w * 32 + fi * 16 + l16 * 4 + r;
                int j = fj * 16 + l15;
                Ub[i * 128 + j] = (_Float16)acc[fi][fj][r];
            }
}

// ---------------------------------------------------------------------------
// R2: chunk-boundary state scan, parallel over (bh, 2048-elem slices).
// ---------------------------------------------------------------------------
__global__ __launch_bounds__(256) void r2_kernel(const _Float16* __restrict__ U,
                                                 _Float16* __restrict__ S,
                                                 const float* __restrict__ A_log)
{
    const int blk = blockIdx.x;
    const int bh = blk >> 3, part = blk & 7, h = bh & 15;
    const float decay = sigmoidf_(A_log[h]);
    const float d64 = __expf(64.0f * logf(decay));
    const size_t base = ((size_t)bh << 19) + (size_t)part * 2048 + (size_t)threadIdx.x * 8;
    const half8* Up = (const half8*)(U + base);
    half8* Sp = (half8*)(S + base);

    float st[8] = {0, 0, 0, 0, 0, 0, 0, 0};
    half8 n0 = Up[0];
    half8 n1 = Up[2048];
    for (int c = 0; c < 32; ++c) {
        half8 cur = n0;
        n0 = n1;
        if (c + 2 < 32) n1 = Up[(size_t)(c + 2) * 2048];
        half8 so;
#pragma unroll
        for (int i = 0; i < 8; ++i) {
            so[i] = (_Float16)st[i];
            st[i] = d64 * st[i] + (float)cur[i];
        }
        Sp[(size_t)c * 2048] = so;
    }
}

// ---------------------------------------------------------------------------
// R3: per (bh, chunk): out = mask(QK^T)V + rowscale(Q S^T); gate fused.
// ---------------------------------------------------------------------------
__global__ __launch_bounds__(256) void r3_kernel(const _Float16* __restrict__ qh,
                                                 const _Float16* __restrict__ kh,
                                                 const _Float16* __restrict__ vh,
                                                 const _Float16* __restrict__ S,
                                                 const _Float16* __restrict__ pg,
                                                 const float* __restrict__ A_log,
                                                 const float* __restrict__ beta,
                                                 _Float16* __restrict__ gated)
{
    const int c = blockIdx.x & 31, bh = blockIdx.x >> 5;
    const int h = bh & 15, b = bh >> 4;
    const float decay = sigmoidf_(A_log[h]);
    const float bet = sigmoidf_(beta[h]);
    const float ld = logf(decay);

    __shared__ _Float16 vt[128][72];
    __shared__ _Float16 ps[64][72];

    const int tid = threadIdx.x;
    const size_t base = ((size_t)(b * T_ + c * 64) * H_ + h) * 128;
    for (int rep = 0; rep < 32; ++rep) {
        int idx = rep * 256 + tid;
        int s = idx >> 7, n = idx & 127;
        vt[n][s] = vh[base + (size_t)s * DIM_ + n];
    }
    __syncthreads();

    const int lane = tid & 63, w = tid >> 6;
    const int l15 = lane & 15, l16 = lane >> 4;

    const _Float16* qrow = qh + base + (size_t)(w * 16 + l15) * DIM_;
    half8 af[4];
#pragma unroll
    for (int kd = 0; kd < 4; ++kd) af[kd] = *(const half8*)(qrow + kd * 32 + l16 * 8);

    f32x4 pacc[4] = {};
    const _Float16* kb = kh + base;
#pragma unroll
    for (int sf = 0; sf < 4; ++sf)
#pragma unroll
        for (int kd = 0; kd < 4; ++kd) {
            half8 bf = *(const half8*)(kb + (size_t)(sf * 16 + l15) * DIM_ + kd * 32 + l16 * 8);
            pacc[sf] = __builtin_amdgcn_mfma_f32_16x16x32_f16(af[kd], bf, pacc[sf], 0, 0, 0);
        }
#pragma unroll
    for (int sf = 0; sf < 4; ++sf)
#pragma unroll
        for (int r = 0; r < 4; ++r) {
            int tl = w * 16 + l16 * 4 + r;
            int s = sf * 16 + l15;
            float f = (s <= tl) ? bet * __expf(ld * (float)(tl - s)) : 0.0f;
            ps[tl][s] = (_Float16)(pacc[sf][r] * f);
        }
    __syncthreads();

    half8 pf[2];
#pragma unroll
    for (int ks = 0; ks < 2; ++ks)
        pf[ks] = *(const half8*)&ps[w * 16 + l15][ks * 32 + l16 * 8];

    f32x4 acc1[8] = {};
    f32x4 acc2[8] = {};
    const _Float16* Sb = S + (((size_t)blockIdx.x) << 14);
#pragma unroll
    for (int nf = 0; nf < 8; ++nf) {
#pragma unroll
        for (int kd = 0; kd < 4; ++kd) {
            half8 bf = *(const half8*)(Sb + (size_t)(nf * 16 + l15) * 128 + kd * 32 + l16 * 8);
            acc1[nf] = __builtin_amdgcn_mfma_f32_16x16x32_f16(af[kd], bf, acc1[nf], 0, 0, 0);
        }
#pragma unroll
        for (int ks = 0; ks < 2; ++ks) {
            half8 bf = *(const half8*)&vt[nf * 16 + l15][ks * 32 + l16 * 8];
            acc2[nf] = __builtin_amdgcn_mfma_f32_16x16x32_f16(pf[ks], bf, acc2[nf], 0, 0, 0);
        }
    }
#pragma unroll
    for (int nf = 0; nf < 8; ++nf)
#pragma unroll
        for (int r = 0; r < 4; ++r) {
            int tl = w * 16 + l16 * 4 + r;
            int n = nf * 16 + l15;
            size_t row = (size_t)(b * T_ + c * 64 + tl);
            float o = acc2[nf][r] + __expf(ld * (float)(tl + 1)) * acc1[nf][r];
            float g = (float)pg[row * DIM_ + h * 128 + n];
            gated[row * DIM_ + h * 128 + n] = (_Float16)(o * sigmoidf_(g));
        }
}

// ---------------------------------------------------------------------------
extern "C" void kernel_launch(void* const* d_in, const int* in_sizes, int n_in,
                              void* d_out, int out_size, void* d_ws, size_t ws_size,
                              hipStream_t stream)
{
    const float* x     = (const float*)d_in[0];
    const float* Wq    = (const float*)d_in[1];
    const float* Wk    = (const float*)d_in[2];
    const float* Wv    = (const float*)d_in[3];
    const float* Wo    = (const float*)d_in[4];
    const float* Wg    = (const float*)d_in[5];
    const float* qw    = (const float*)d_in[6];
    const float* qb    = (const float*)d_in[7];
    const float* kw    = (const float*)d_in[8];
    const float* kb    = (const float*)d_in[9];
    const float* vw    = (const float*)d_in[10];
    const float* vb    = (const float*)d_in[11];
    const float* beta  = (const float*)d_in[12];
    const float* A_log = (const float*)d_in[13];
    float* out = (float*)d_out;

    char* wsb = (char*)d_ws;
    const size_t WT  = (size_t)DIM_ * DIM_ * 2;
    const size_t SZ  = (size_t)B_ * T_ * DIM_;
    const size_t SZH = SZ * 2;

    _Float16* wtq = (_Float16*)(wsb + 0 * WT);    // wtq..wtg contiguous = Bt[8192][2048]
    _Float16* wto = (_Float16*)(wsb + 4 * WT);
    char* pbase = wsb + 5 * WT;
    _Float16* pq = (_Float16*)(pbase + 0 * SZH);
    _Float16* pk = (_Float16*)(pbase + 1 * SZH);
    _Float16* pv = (_Float16*)(pbase + 2 * SZH);
    _Float16* xh = (_Float16*)(pbase + 3 * SZH);
    _Float16* pg = (_Float16*)(pbase + 4 * SZH);
    _Float16* qh = (_Float16*)(pbase + 5 * SZH);
    _Float16* kh = (_Float16*)(pbase + 6 * SZH);
    _Float16* vh = (_Float16*)(pbase + 7 * SZH);
    _Float16* U     = pq;  // 32 MB, spans pq+pk (dead after convs)
    _Float16* Sst   = pv;  // 32 MB, spans pv+xh (dead after conv_v / GEMMs)
    _Float16* gated = pq;  // 16 MB, U dead after r2

    cvt_f16<<<(int)(SZ / 2048), 256, 0, stream>>>(x, xh);
    wconvT5<<<dim3(32, 32, 5), 256, 0, stream>>>(Wq, Wk, Wv, Wg, Wo, wtq);

    // fused projections: M=4096, N=8192 (q|k|v|g): 16x32 = 512 tiles of 256^2
    gemm256<256, _Float16><<<512, 512, 0, stream>>>(xh, wtq, pq, pk, pv, pg,
                                                    DIM_, 32, 64);

    conv_qv<<<dim3((int)(SZ / 256), 2), 256, 0, stream>>>(pq, pv, qw, qb, vw, vb, qh, vh);
    conv_knorm<<<(B_ * T_ * H_) / 4, 256, 0, stream>>>(pk, kw, kb, kh);

    r1_kernel<<<B_ * H_ * 32, 256, 0, stream>>>(kh, vh, A_log, beta, U);
    r2_kernel<<<256, 256, 0, stream>>>(U, Sst, A_log);
    r3_kernel<<<B_ * H_ * 32, 256, 0, stream>>>(qh, kh, vh, Sst, pg, A_log, beta, gated);

    // out = gated @ Wo : M=4096, N=2048 -> 32x8 = 256 tiles of 128x256
    gemm256<128, float><<<256, 512, 0, stream>>>(gated, wto, out, out, out, out,
                                                 DIM_, 8, 32);
}

// Round 6
// 422.858 us; speedup vs baseline: 8.9128x; 1.0301x over previous
//
#include <hip/hip_runtime.h>
#include <math.h>

#define B_   2
#define T_   2048
#define DIM_ 2048
#define H_   16

typedef __attribute__((ext_vector_type(8))) _Float16 half8;
typedef __attribute__((ext_vector_type(4))) _Float16 half4;
typedef __attribute__((ext_vector_type(4))) float f32x4;

__device__ __forceinline__ float sigmoidf_(float x) { return 1.0f / (1.0f + __expf(-x)); }

__device__ __forceinline__ void gload16(const _Float16* g, _Float16* l) {
    __builtin_amdgcn_global_load_lds((const __attribute__((address_space(1))) void*)g,
                                     (__attribute__((address_space(3))) void*)l, 16, 0, 0);
}

// ---------------------------------------------------------------------------
// fp32 -> f16 elementwise convert (8/thread)
// ---------------------------------------------------------------------------
__global__ __launch_bounds__(256) void cvt_f16(const float* __restrict__ in,
                                               _Float16* __restrict__ out)
{
    size_t i = ((size_t)blockIdx.x * 256 + threadIdx.x) * 8;
    float4 a = *(const float4*)(in + i);
    float4 b = *(const float4*)(in + i + 4);
    half8 h;
    h[0] = (_Float16)a.x; h[1] = (_Float16)a.y; h[2] = (_Float16)a.z; h[3] = (_Float16)a.w;
    h[4] = (_Float16)b.x; h[5] = (_Float16)b.y; h[6] = (_Float16)b.z; h[7] = (_Float16)b.w;
    *(half8*)(out + i) = h;
}

// ---------------------------------------------------------------------------
// 5 weight transposes fused: W[K][N] fp32 -> Wt[N][K] f16, blockIdx.z selects.
// ---------------------------------------------------------------------------
__global__ __launch_bounds__(256) void wconvT5(const float* __restrict__ W0,
                                               const float* __restrict__ W1,
                                               const float* __restrict__ W2,
                                               const float* __restrict__ W3,
                                               const float* __restrict__ W4,
                                               _Float16* __restrict__ base)
{
    __shared__ float t[64][65];
    const int z = blockIdx.z;
    const float* W = z == 0 ? W0 : z == 1 ? W1 : z == 2 ? W2 : z == 3 ? W3 : W4;
    _Float16* Wt = base + (size_t)z * DIM_ * DIM_;
    const int c = threadIdx.x & 63;
    const int r0 = threadIdx.x >> 6;
    const int n0 = blockIdx.x * 64, k0 = blockIdx.y * 64;
#pragma unroll
    for (int i = 0; i < 16; ++i) {
        int r = i * 4 + r0;
        t[r][c] = W[(size_t)(k0 + r) * DIM_ + n0 + c];
    }
    __syncthreads();
#pragma unroll
    for (int i = 0; i < 16; ++i) {
        int r = i * 4 + r0;
        Wt[(size_t)(n0 + r) * DIM_ + k0 + c] = (_Float16)t[c][r];
    }
}

// ---------------------------------------------------------------------------
// 8-phase pipelined MFMA GEMM (m201 schedule, plain HIP):
// BM x 256 tile, BK=64, 2 K-tiles/iter (dbuf0=even tile, dbuf1=odd tile),
// 8 waves (2M x 4N). Per phase: ds_read one C-quadrant's frags (B: all 8 at
// quadrant 0, kept in regs) + stage exactly one safe half-tile; barrier;
// lgkmcnt(0); setprio(1); MFMA quadrant; setprio(0); barrier. Counted
// vmcnt(4) at phases 3/7 only (= the 2 B-half-tile stages allowed in flight).
// LDS: 3-bit XOR swizzle slot^=row&7, matching pre-swizzled global source.
// C = A[M,K] * Bt[N,K]^T ; N split into 2048-col output segments.
// ---------------------------------------------------------------------------
template <int BM, typename OT>
__global__ __launch_bounds__(512, 1) void gemm8ph(const _Float16* __restrict__ A,
                                                  const _Float16* __restrict__ Bt,
                                                  OT* __restrict__ C0, OT* __restrict__ C1,
                                                  OT* __restrict__ C2, OT* __restrict__ C3,
                                                  int K, int nx, int cpx)
{
    constexpr int MF  = BM / 32;          // A frags per wave (wave M rows = BM/2)
    constexpr int AQ  = MF / 4;           // A frags per phase (quadrant)
    constexpr int ASZ = BM * 64;          // A region halfs per dbuf
    constexpr int DSZ = (BM + 256) * 64;  // halfs per dbuf (A + B)
    __shared__ _Float16 lds[2 * DSZ];

    const int tid = threadIdx.x;
    const int lane = tid & 63, w = tid >> 6;
    const int wr = w >> 2, wc = w & 3;
    const int l15 = lane & 15, l16 = lane >> 4;

    const int bid = blockIdx.x;
    const int swz = (bid & 7) * cpx + (bid >> 3);   // XCD swizzle (nwg%8==0)
    const int bm = (swz / nx) * BM, bn = (swz % nx) * 256;

    // staging addressing: linear LDS dest (tid*16B), pre-swizzled global src.
    // Within a 64-half row: slot s (8 halfs each); phys slot = s ^ (row&7).
    const int r0 = tid >> 3;                         // row within 64-row round
    const int c0 = ((tid & 7) ^ (r0 & 7)) * 8;       // pre-swizzled col (halfs)
    const _Float16* Ab = A + (size_t)(bm + r0) * K + c0;
    const _Float16* Bb = Bt + (size_t)(bn + r0) * K + c0;

#define STAGE_A(d, kt) do { _Pragma("unroll")                                    \
    for (int u = 0; u < BM / 64; ++u)                                            \
        gload16(Ab + (size_t)(u * 64) * K + (size_t)(kt) * 64,                   \
                lds + (d) * DSZ + u * 4096 + tid * 8); } while (0)
#define STAGE_B(d, h, kt) do {                                                   \
    gload16(Bb + (size_t)((h) * 128) * K + (size_t)(kt) * 64,                    \
            lds + (d) * DSZ + ASZ + (h) * 8192 + tid * 8);                       \
    gload16(Bb + (size_t)((h) * 128 + 64) * K + (size_t)(kt) * 64,               \
            lds + (d) * DSZ + ASZ + (h) * 8192 + 4096 + tid * 8); } while (0)
#define VMW(n) asm volatile("s_waitcnt vmcnt(" #n ")" ::: "memory")

    // fragment read offsets (halfs), same XOR swizzle
    int aoff[MF][2], boff[4][2];
#pragma unroll
    for (int m = 0; m < MF; ++m) {
        int R = wr * (BM / 2) + m * 16 + l15;
#pragma unroll
        for (int ks = 0; ks < 2; ++ks)
            aoff[m][ks] = R * 64 + (((ks * 4 + l16) ^ (R & 7)) * 8);
    }
#pragma unroll
    for (int n = 0; n < 4; ++n) {
        int R = wc * 64 + n * 16 + l15;
#pragma unroll
        for (int ks = 0; ks < 2; ++ks)
            boff[n][ks] = ASZ + R * 64 + (((ks * 4 + l16) ^ (R & 7)) * 8);
    }

    f32x4 acc[MF][4] = {};
    half8 bfr[4][2];
    const int nj = K >> 7;   // 128 K per iteration

    // prologue: A(0)->d0, B(0)->d0, B(1)->d1; wait all but B(1)
    STAGE_A(0, 0);
    STAGE_B(0, 0, 0); STAGE_B(0, 1, 0);
    STAGE_B(1, 0, 1); STAGE_B(1, 1, 1);
    VMW(4);
    __builtin_amdgcn_s_barrier();
    __builtin_amdgcn_sched_barrier(0);

#define PH(TT, Q, STAGECODE, VMCODE) do {                                        \
    const int dB_ = (TT) * DSZ;                                                  \
    half8 af_[AQ][2];                                                            \
    if ((Q) == 0) {                                                              \
        _Pragma("unroll") for (int n_ = 0; n_ < 4; ++n_)                         \
        _Pragma("unroll") for (int ks_ = 0; ks_ < 2; ++ks_)                      \
            bfr[n_][ks_] = *(const half8*)(lds + dB_ + boff[n_][ks_]);           \
    }                                                                            \
    _Pragma("unroll") for (int a_ = 0; a_ < AQ; ++a_)                            \
    _Pragma("unroll") for (int ks_ = 0; ks_ < 2; ++ks_)                          \
        af_[a_][ks_] = *(const half8*)(lds + dB_ + aoff[(Q) * AQ + a_][ks_]);    \
    STAGECODE;                                                                   \
    __builtin_amdgcn_s_barrier();                                                \
    asm volatile("s_waitcnt lgkmcnt(0)" ::: "memory");                           \
    __builtin_amdgcn_sched_barrier(0);                                           \
    __builtin_amdgcn_s_setprio(1);                                               \
    _Pragma("unroll") for (int ks_ = 0; ks_ < 2; ++ks_)                          \
    _Pragma("unroll") for (int a_ = 0; a_ < AQ; ++a_)                            \
    _Pragma("unroll") for (int n_ = 0; n_ < 4; ++n_)                             \
        acc[(Q) * AQ + a_][n_] = __builtin_amdgcn_mfma_f32_16x16x32_f16(         \
            af_[a_][ks_], bfr[n_][ks_], acc[(Q) * AQ + a_][n_], 0, 0, 0);        \
    __builtin_amdgcn_s_setprio(0);                                               \
    __builtin_amdgcn_sched_barrier(0);                                           \
    VMCODE;                                                                      \
    __builtin_amdgcn_s_barrier();                                                \
} while (0)

    for (int j = 0; j < nj; ++j) {
        const bool pf = (j + 1 < nj);
        const int t1 = 2 * j + 1, tn0 = 2 * j + 2, tn1 = 2 * j + 3;
        // ---- K-tile 2j (dbuf0) ----
        PH(0, 0, { STAGE_A(1, t1); }, {});
        PH(0, 1, { if (pf) STAGE_B(0, 0, tn0); }, {});
        PH(0, 2, { if (pf) STAGE_B(0, 1, tn0); }, {});
        PH(0, 3, {}, { if (pf) { VMW(4); } else { VMW(0); } });
        // ---- K-tile 2j+1 (dbuf1) ----
        PH(1, 0, { if (pf) STAGE_A(0, tn0); }, {});
        PH(1, 1, {}, {});
        PH(1, 2, { if (pf) STAGE_B(1, 0, tn1); }, {});
        PH(1, 3, { if (pf) STAGE_B(1, 1, tn1); }, { if (pf) VMW(4); });
    }
#undef PH
#undef STAGE_A
#undef STAGE_B
#undef VMW

    const int sel = bn >> 11;
    OT* __restrict__ C = sel == 0 ? C0 : sel == 1 ? C1 : sel == 2 ? C2 : C3;
    const int ccb = (bn & 2047) + wc * 64;
    const int crb = bm + wr * (BM / 2);
#pragma unroll
    for (int m = 0; m < MF; ++m)
#pragma unroll
        for (int n = 0; n < 4; ++n)
#pragma unroll
            for (int r = 0; r < 4; ++r)
                C[(size_t)(crb + m * 16 + l16 * 4 + r) * 2048 + ccb + n * 16 + l15] =
                    (OT)acc[m][n][r];
}

// ---------------------------------------------------------------------------
// Depthwise causal conv K=4 + bias (+silu). blockIdx.y: 0 = q(silu), 1 = v.
// ---------------------------------------------------------------------------
__global__ __launch_bounds__(256) void conv_qv(const _Float16* __restrict__ qin,
                                               const _Float16* __restrict__ vin,
                                               const float* __restrict__ qw,
                                               const float* __restrict__ qb,
                                               const float* __restrict__ vw,
                                               const float* __restrict__ vb,
                                               _Float16* __restrict__ qo,
                                               _Float16* __restrict__ vo)
{
    const int act = blockIdx.y == 0;
    const _Float16* xin = act ? qin : vin;
    const float* w = act ? qw : vw;
    const float* bias = act ? qb : vb;
    _Float16* y = act ? qo : vo;

    size_t idx = (size_t)blockIdx.x * 256 + threadIdx.x;
    int cc = (int)(idx & (DIM_ - 1));
    int t = (int)((idx >> 11) & (T_ - 1));
    int b = (int)(idx >> 22);
    float acc = bias[cc];
    const _Float16* xc = xin + (size_t)b * T_ * DIM_ + cc;
#pragma unroll
    for (int j = 0; j < 4; ++j) {
        int ts = t - 3 + j;
        if (ts >= 0) acc += (float)xc[(size_t)ts * DIM_] * w[cc * 4 + j];
    }
    if (act) acc = acc * sigmoidf_(acc);
    y[idx] = (_Float16)acc;
}

// ---------------------------------------------------------------------------
// conv_k + silu + L2-normalize fused: one wave per (b,t,h) row, 2 ch/lane.
// ---------------------------------------------------------------------------
__global__ __launch_bounds__(256) void conv_knorm(const _Float16* __restrict__ xin,
                                                  const float* __restrict__ w,
                                                  const float* __restrict__ bias,
                                                  _Float16* __restrict__ kh)
{
    int lane = threadIdx.x & 63, wv = threadIdx.x >> 6;
    size_t r = (size_t)blockIdx.x * 4 + wv;   // (b*T+t)*H + h
    int h = (int)(r & 15);
    size_t gr = r >> 4;                       // b*T + t
    int t = (int)(gr & (T_ - 1));
    int c0 = h * 128 + lane * 2;

    float a0 = bias[c0], a1 = bias[c0 + 1];
#pragma unroll
    for (int j = 0; j < 4; ++j) {
        int ts = t - 3 + j;
        if (ts >= 0) {
            const _Float16* p = xin + (gr - 3 + j) * DIM_ + c0;
            a0 += (float)p[0] * w[c0 * 4 + j];
            a1 += (float)p[1] * w[(c0 + 1) * 4 + j];
        }
    }
    a0 = a0 * sigmoidf_(a0);
    a1 = a1 * sigmoidf_(a1);
    float ss = a0 * a0 + a1 * a1;
#pragma unroll
    for (int off = 1; off < 64; off <<= 1) ss += __shfl_xor(ss, off);
    float sc = 1.0f / fmaxf(sqrtf(ss), 1e-12f);
    kh[gr * DIM_ + c0]     = (_Float16)(a0 * sc);
    kh[gr * DIM_ + c0 + 1] = (_Float16)(a1 * sc);
}

// ---------------------------------------------------------------------------
// R1: per (bh, chunk) U_c = sum_s bet*decay^(63-s) * v_s k_s^T  (128x128 f16)
// ---------------------------------------------------------------------------
__global__ __launch_bounds__(256) void r1_kernel(const _Float16* __restrict__ kh,
                                                 const _Float16* __restrict__ vh,
                                                 const float* __restrict__ A_log,
                                                 const float* __restrict__ beta,
                                                 _Float16* __restrict__ U)
{
    const int c = blockIdx.x & 31, bh = blockIdx.x >> 5;
    const int h = bh & 15, b = bh >> 4;
    const float decay = sigmoidf_(A_log[h]);
    const float bet = sigmoidf_(beta[h]);
    const float ld = logf(decay);

    __shared__ _Float16 kt[128][72];
    __shared__ _Float16 vt[128][72];

    const int tid = threadIdx.x;
    const size_t base = ((size_t)(b * T_ + c * 64) * H_ + h) * 128;
    for (int rep = 0; rep < 32; ++rep) {
        int idx = rep * 256 + tid;
        int s = idx >> 7, i = idx & 127;
        float kv = (float)kh[base + (size_t)s * DIM_ + i];
        float vv = (float)vh[base + (size_t)s * DIM_ + i];
        kt[i][s] = (_Float16)kv;
        vt[i][s] = (_Float16)(bet * __expf(ld * (float)(63 - s)) * vv);
    }
    __syncthreads();

    const int lane = tid & 63, w = tid >> 6;
    const int l15 = lane & 15, l16 = lane >> 4;
    f32x4 acc[2][8] = {};
#pragma unroll
    for (int ks = 0; ks < 2; ++ks) {
        half8 a0 = *(const half8*)&vt[w * 32 + l15][ks * 32 + l16 * 8];
        half8 a1 = *(const half8*)&vt[w * 32 + 16 + l15][ks * 32 + l16 * 8];
#pragma unroll
        for (int fj = 0; fj < 8; ++fj) {
            half8 bf = *(const half8*)&kt[fj * 16 + l15][ks * 32 + l16 * 8];
            acc[0][fj] = __builtin_amdgcn_mfma_f32_16x16x32_f16(a0, bf, acc[0][fj], 0, 0, 0);
            acc[1][fj] = __builtin_amdgcn_mfma_f32_16x16x32_f16(a1, bf, acc[1][fj], 0, 0, 0);
        }
    }
    _Float16* Ub = U + (((size_t)blockIdx.x) << 14);
#pragma unroll
    for (int fi = 0; fi < 2; ++fi)
#pragma unroll
        for (int fj = 0; fj < 8; ++fj)
#pragma unroll
            for (int r = 0; r < 4; ++r) {
                int i = w * 32 + fi * 16 + l16 * 4 + r;
                int j = fj * 16 + l15;
                Ub[i * 128 + j] = (_Float16)acc[fi][fj][r];
            }
}

// ---------------------------------------------------------------------------
// R2: chunk-boundary state scan, parallel over (bh, 2048-elem slices).
// ---------------------------------------------------------------------------
__global__ __launch_bounds__(256) void r2_kernel(const _Float16* __restrict__ U,
                                                 _Float16* __restrict__ S,
                                                 const float* __restrict__ A_log)
{
    const int blk = blockIdx.x;
    const int bh = blk >> 3, part = blk & 7, h = bh & 15;
    const float decay = sigmoidf_(A_log[h]);
    const float d64 = __expf(64.0f * logf(decay));
    const size_t base = ((size_t)bh << 19) + (size_t)part * 2048 + (size_t)threadIdx.x * 8;
    const half8* Up = (const half8*)(U + base);
    half8* Sp = (half8*)(S + base);

    float st[8] = {0, 0, 0, 0, 0, 0, 0, 0};
    half8 n0 = Up[0];
    half8 n1 = Up[2048];
    for (int c = 0; c < 32; ++c) {
        half8 cur = n0;
        n0 = n1;
        if (c + 2 < 32) n1 = Up[(size_t)(c + 2) * 2048];
        half8 so;
#pragma unroll
        for (int i = 0; i < 8; ++i) {
            so[i] = (_Float16)st[i];
            st[i] = d64 * st[i] + (float)cur[i];
        }
        Sp[(size_t)c * 2048] = so;
    }
}

// ---------------------------------------------------------------------------
// R3: per (bh, chunk): out = mask(QK^T)V + rowscale(Q S^T); gate fused.
// ---------------------------------------------------------------------------
__global__ __launch_bounds__(256) void r3_kernel(const _Float16* __restrict__ qh,
                                                 const _Float16* __restrict__ kh,
                                                 const _Float16* __restrict__ vh,
                                                 const _Float16* __restrict__ S,
                                                 const _Float16* __restrict__ pg,
                                                 const float* __restrict__ A_log,
                                                 const float* __restrict__ beta,
                                                 _Float16* __restrict__ gated)
{
    const int c = blockIdx.x & 31, bh = blockIdx.x >> 5;
    const int h = bh & 15, b = bh >> 4;
    const float decay = sigmoidf_(A_log[h]);
    const float bet = sigmoidf_(beta[h]);
    const float ld = logf(decay);

    __shared__ _Float16 vt[128][72];
    __shared__ _Float16 ps[64][72];

    const int tid = threadIdx.x;
    const size_t base = ((size_t)(b * T_ + c * 64) * H_ + h) * 128;
    for (int rep = 0; rep < 32; ++rep) {
        int idx = rep * 256 + tid;
        int s = idx >> 7, n = idx & 127;
        vt[n][s] = vh[base + (size_t)s * DIM_ + n];
    }
    __syncthreads();

    const int lane = tid & 63, w = tid >> 6;
    const int l15 = lane & 15, l16 = lane >> 4;

    const _Float16* qrow = qh + base + (size_t)(w * 16 + l15) * DIM_;
    half8 af[4];
#pragma unroll
    for (int kd = 0; kd < 4; ++kd) af[kd] = *(const half8*)(qrow + kd * 32 + l16 * 8);

    f32x4 pacc[4] = {};
    const _Float16* kb = kh + base;
#pragma unroll
    for (int sf = 0; sf < 4; ++sf)
#pragma unroll
        for (int kd = 0; kd < 4; ++kd) {
            half8 bf = *(const half8*)(kb + (size_t)(sf * 16 + l15) * DIM_ + kd * 32 + l16 * 8);
            pacc[sf] = __builtin_amdgcn_mfma_f32_16x16x32_f16(af[kd], bf, pacc[sf], 0, 0, 0);
        }
#pragma unroll
    for (int sf = 0; sf < 4; ++sf)
#pragma unroll
        for (int r = 0; r < 4; ++r) {
            int tl = w * 16 + l16 * 4 + r;
            int s = sf * 16 + l15;
            float f = (s <= tl) ? bet * __expf(ld * (float)(tl - s)) : 0.0f;
            ps[tl][s] = (_Float16)(pacc[sf][r] * f);
        }
    __syncthreads();

    half8 pf[2];
#pragma unroll
    for (int ks = 0; ks < 2; ++ks)
        pf[ks] = *(const half8*)&ps[w * 16 + l15][ks * 32 + l16 * 8];

    f32x4 acc1[8] = {};
    f32x4 acc2[8] = {};
    const _Float16* Sb = S + (((size_t)blockIdx.x) << 14);
#pragma unroll
    for (int nf = 0; nf < 8; ++nf) {
#pragma unroll
        for (int kd = 0; kd < 4; ++kd) {
            half8 bf = *(const half8*)(Sb + (size_t)(nf * 16 + l15) * 128 + kd * 32 + l16 * 8);
            acc1[nf] = __builtin_amdgcn_mfma_f32_16x16x32_f16(af[kd], bf, acc1[nf], 0, 0, 0);
        }
#pragma unroll
        for (int ks = 0; ks < 2; ++ks) {
            half8 bf = *(const half8*)&vt[nf * 16 + l15][ks * 32 + l16 * 8];
            acc2[nf] = __builtin_amdgcn_mfma_f32_16x16x32_f16(pf[ks], bf, acc2[nf], 0, 0, 0);
        }
    }
#pragma unroll
    for (int nf = 0; nf < 8; ++nf)
#pragma unroll
        for (int r = 0; r < 4; ++r) {
            int tl = w * 16 + l16 * 4 + r;
            int n = nf * 16 + l15;
            size_t row = (size_t)(b * T_ + c * 64 + tl);
            float o = acc2[nf][r] + __expf(ld * (float)(tl + 1)) * acc1[nf][r];
            float g = (float)pg[row * DIM_ + h * 128 + n];
            gated[row * DIM_ + h * 128 + n] = (_Float16)(o * sigmoidf_(g));
        }
}

// ---------------------------------------------------------------------------
extern "C" void kernel_launch(void* const* d_in, const int* in_sizes, int n_in,
                              void* d_out, int out_size, void* d_ws, size_t ws_size,
                              hipStream_t stream)
{
    const float* x     = (const float*)d_in[0];
    const float* Wq    = (const float*)d_in[1];
    const float* Wk    = (const float*)d_in[2];
    const float* Wv    = (const float*)d_in[3];
    const float* Wo    = (const float*)d_in[4];
    const float* Wg    = (const float*)d_in[5];
    const float* qw    = (const float*)d_in[6];
    const float* qb    = (const float*)d_in[7];
    const float* kw    = (const float*)d_in[8];
    const float* kb    = (const float*)d_in[9];
    const float* vw    = (const float*)d_in[10];
    const float* vb    = (const float*)d_in[11];
    const float* beta  = (const float*)d_in[12];
    const float* A_log = (const float*)d_in[13];
    float* out = (float*)d_out;

    char* wsb = (char*)d_ws;
    const size_t WT  = (size_t)DIM_ * DIM_ * 2;
    const size_t SZ  = (size_t)B_ * T_ * DIM_;
    const size_t SZH = SZ * 2;

    _Float16* wtq = (_Float16*)(wsb + 0 * WT);    // wtq..wtg contiguous = Bt[8192][2048]
    _Float16* wto = (_Float16*)(wsb + 4 * WT);
    char* pbase = wsb + 5 * WT;
    _Float16* pq = (_Float16*)(pbase + 0 * SZH);
    _Float16* pk = (_Float16*)(pbase + 1 * SZH);
    _Float16* pv = (_Float16*)(pbase + 2 * SZH);
    _Float16* xh = (_Float16*)(pbase + 3 * SZH);
    _Float16* pg = (_Float16*)(pbase + 4 * SZH);
    _Float16* qh = (_Float16*)(pbase + 5 * SZH);
    _Float16* kh = (_Float16*)(pbase + 6 * SZH);
    _Float16* vh = (_Float16*)(pbase + 7 * SZH);
    _Float16* U     = pq;  // 32 MB, spans pq+pk (dead after convs)
    _Float16* Sst   = pv;  // 32 MB, spans pv+xh (dead after conv_v / GEMMs)
    _Float16* gated = pq;  // 16 MB, U dead after r2

    cvt_f16<<<(int)(SZ / 2048), 256, 0, stream>>>(x, xh);
    wconvT5<<<dim3(32, 32, 5), 256, 0, stream>>>(Wq, Wk, Wv, Wg, Wo, wtq);

    // fused projections: M=4096, N=8192 (q|k|v|g): 16x32 = 512 tiles of 256^2
    gemm8ph<256, _Float16><<<512, 512, 0, stream>>>(xh, wtq, pq, pk, pv, pg,
                                                    DIM_, 32, 64);

    conv_qv<<<dim3((int)(SZ / 256), 2), 256, 0, stream>>>(pq, pv, qw, qb, vw, vb, qh, vh);
    conv_knorm<<<(B_ * T_ * H_) / 4, 256, 0, stream>>>(pk, kw, kb, kh);

    r1_kernel<<<B_ * H_ * 32, 256, 0, stream>>>(kh, vh, A_log, beta, U);
    r2_kernel<<<256, 256, 0, stream>>>(U, Sst, A_log);
    r3_kernel<<<B_ * H_ * 32, 256, 0, stream>>>(qh, kh, vh, Sst, pg, A_log, beta, gated);

    // out = gated @ Wo : M=4096, N=2048 -> 32x8 = 256 tiles of 128x256
    gemm8ph<128, float><<<256, 512, 0, stream>>>(gated, wto, out, out, out, out,
                                                 DIM_, 8, 32);
}